// Round 1
// baseline (1542.022 us; speedup 1.0000x reference)
//
#include <hip/hip_runtime.h>
#include <hip/hip_bf16.h>

#define N_NODES 100000
#define N_EDGES 600000

typedef __hip_bfloat16 bf16;

__device__ __forceinline__ float4 ld4(const float* p){ return *(const float4*)p; }

__device__ __forceinline__ float sigm(float v){ return 1.0f/(1.0f + __expf(-v)); }
__device__ __forceinline__ float tanh_fast(float v){
  float e = __expf(-2.0f*fabsf(v));
  float r = (1.0f - e)/(1.0f + e);
  return copysignf(r, v);
}

__device__ __forceinline__ void fma4x4(float (&acc)[4][4], float4 a, float4 b){
  float av[4] = {a.x,a.y,a.z,a.w};
  float bv[4] = {b.x,b.y,b.z,b.w};
#pragma unroll
  for (int i=0;i<4;++i)
#pragma unroll
  for (int j=0;j<4;++j) acc[i][j] = fmaf(av[i], bv[j], acc[i][j]);
}

// stage a 64-row x 16-col tile of row-major A (leading dim ld) transposed into s[k][m] (s is [16][64])
__device__ __forceinline__ void stageT(float* s, const float* __restrict__ A, int row0, int rowLim, int k0, int ld){
  const int t = threadIdx.x;
  const int m = t >> 2, k4 = (t & 3) << 2;
  float4 v = make_float4(0.f,0.f,0.f,0.f);
  const int r = row0 + m;
  if (r < rowLim) v = ld4(A + (size_t)r*ld + k0 + k4);
  s[(k4+0)*64 + m] = v.x;
  s[(k4+1)*64 + m] = v.y;
  s[(k4+2)*64 + m] = v.z;
  s[(k4+3)*64 + m] = v.w;
}

// -------------------- GRU (fused gi, gh, gates) --------------------
__global__ __launch_bounds__(256) void k_gru(const float* __restrict__ x, const float* __restrict__ h,
    const float* __restrict__ Wih, const float* __restrict__ Whh,
    const float* __restrict__ bih, const float* __restrict__ bhh,
    float* __restrict__ hout)
{
  __shared__ float Ax[16*64], Ah[16*64], Bs[6][16*64];
  const int i0 = blockIdx.x*64, j0 = blockIdx.y*64;
  const int t = threadIdx.x, tx = t & 15, ty = t >> 4;
  float acc[6][4][4] = {};
  for (int kt = 0; kt < 128; kt += 16) {
    __syncthreads();
    stageT(Ax, x, i0, N_NODES, kt, 128);
    stageT(Ah, h, i0, N_NODES, kt, 128);
#pragma unroll
    for (int g = 0; g < 3; ++g) {
      stageT(Bs[g],   Wih + g*128*128, j0, 1<<30, kt, 128);
      stageT(Bs[3+g], Whh + g*128*128, j0, 1<<30, kt, 128);
    }
    __syncthreads();
#pragma unroll
    for (int k = 0; k < 16; ++k) {
      float4 ax = ld4(Ax + k*64 + ty*4);
      float4 ah = ld4(Ah + k*64 + ty*4);
#pragma unroll
      for (int g = 0; g < 3; ++g) {
        float4 bg = ld4(&Bs[g][k*64 + tx*4]);
        fma4x4(acc[g], ax, bg);
      }
#pragma unroll
      for (int g = 0; g < 3; ++g) {
        float4 bg = ld4(&Bs[3+g][k*64 + tx*4]);
        fma4x4(acc[3+g], ah, bg);
      }
    }
  }
  float biA[3][4], bhA[3][4];
#pragma unroll
  for (int g = 0; g < 3; ++g)
#pragma unroll
    for (int c = 0; c < 4; ++c) {
      biA[g][c] = bih[g*128 + j0 + tx*4 + c];
      bhA[g][c] = bhh[g*128 + j0 + tx*4 + c];
    }
#pragma unroll
  for (int r = 0; r < 4; ++r) {
    const int row = i0 + ty*4 + r;
    if (row < N_NODES) {
      float4 hp = ld4(h + (size_t)row*128 + j0 + tx*4);
      float hpv[4] = {hp.x,hp.y,hp.z,hp.w};
      float o[4];
#pragma unroll
      for (int c = 0; c < 4; ++c) {
        float ir = acc[0][r][c] + biA[0][c];
        float iz = acc[1][r][c] + biA[1][c];
        float in_ = acc[2][r][c] + biA[2][c];
        float hr = acc[3][r][c] + bhA[0][c];
        float hz = acc[4][r][c] + bhA[1][c];
        float hn = acc[5][r][c] + bhA[2][c];
        float rg = sigm(ir + hr);
        float zg = sigm(iz + hz);
        float ng = tanh_fast(in_ + rg*hn);
        o[c] = (1.f - zg)*ng + zg*hpv[c];
      }
      *(float4*)(hout + (size_t)row*128 + j0 + tx*4) = make_float4(o[0],o[1],o[2],o[3]);
    }
  }
}

// -------------------- CSR build --------------------
__global__ void k_count(const int* __restrict__ dst, int* __restrict__ counts){
  int e = blockIdx.x*256 + threadIdx.x;
  if (e < N_EDGES) atomicAdd(&counts[dst[e]], 1);
}

__global__ __launch_bounds__(1024) void k_scan(const int* __restrict__ counts,
    int* __restrict__ offs, int* __restrict__ cursor)
{
  __shared__ int wsum[16];
  __shared__ int cbase;
  const int t = threadIdx.x, lane = t & 63, w = t >> 6;
  if (t == 0) cbase = 0;
  __syncthreads();
  for (int base = 0; base < N_NODES; base += 1024) {
    int i = base + t;
    int v = (i < N_NODES) ? counts[i] : 0;
    int s = v;
#pragma unroll
    for (int d = 1; d < 64; d <<= 1) {
      int u = __shfl_up(s, d, 64);
      if (lane >= d) s += u;
    }
    if (lane == 63) wsum[w] = s;
    __syncthreads();
    int add0 = cbase;
    if (w == 0) {
      int ws = (lane < 16) ? wsum[lane] : 0;
#pragma unroll
      for (int d = 1; d < 16; d <<= 1) {
        int u = __shfl_up(ws, d, 64);
        if (lane >= d) ws += u;
      }
      if (lane < 16) wsum[lane] = ws;
    }
    __syncthreads();
    int wbase = (w == 0) ? 0 : wsum[w-1];
    int excl = add0 + wbase + (s - v);
    if (i < N_NODES) { offs[i] = excl; cursor[i] = excl; }
    __syncthreads();
    if (t == 0) cbase += wsum[15];
    __syncthreads();
  }
  if (t == 0) offs[N_NODES] = cbase;
}

__global__ void k_fill(const int* __restrict__ ei, int* __restrict__ cursor, int* __restrict__ lst){
  int e = blockIdx.x*256 + threadIdx.x;
  if (e < N_EDGES){
    int d = ei[N_EDGES + e];
    int slot = atomicAdd(&cursor[d], 1);
    lst[slot] = ei[e];
  }
}

// -------------------- mean aggregation: one wave per node --------------------
__global__ __launch_bounds__(256) void k_agg(const float* __restrict__ h,
    const int* __restrict__ offs, const int* __restrict__ lst, float* __restrict__ mean)
{
  const int node = blockIdx.x*4 + (threadIdx.x >> 6);
  if (node >= N_NODES) return;
  const int lane = threadIdx.x & 63;
  const int beg = offs[node], end = offs[node+1];
  float ax = 0.f, ay = 0.f;
  const float2* hp = (const float2*)h;
  for (int e = beg; e < end; ++e) {
    int s = lst[e];
    float2 v = hp[(size_t)s*64 + lane];
    ax += v.x; ay += v.y;
  }
  float inv = 1.f / fmaxf((float)(end - beg), 1.f);
  float2 o; o.x = ax*inv; o.y = ay*inv;
  ((float2*)mean)[(size_t)node*64 + lane] = o;
}

// -------------------- SAGE: relu(mean@Wl^T + bl + h@Wr^T) --------------------
__global__ __launch_bounds__(256) void k_sage(const float* __restrict__ mean, const float* __restrict__ h,
    const float* __restrict__ Wl, const float* __restrict__ Wr, const float* __restrict__ bl,
    float* __restrict__ outp)
{
  __shared__ float Am[16*64], Ah[16*64], Bl[16*64], Br[16*64];
  const int i0 = blockIdx.x*64, j0 = blockIdx.y*64;
  const int t = threadIdx.x, tx = t & 15, ty = t >> 4;
  float acc[4][4] = {};
  for (int kt = 0; kt < 128; kt += 16) {
    __syncthreads();
    stageT(Am, mean, i0, N_NODES, kt, 128);
    stageT(Ah, h, i0, N_NODES, kt, 128);
    stageT(Bl, Wl, j0, 1<<30, kt, 128);
    stageT(Br, Wr, j0, 1<<30, kt, 128);
    __syncthreads();
#pragma unroll
    for (int k = 0; k < 16; ++k) {
      fma4x4(acc, ld4(Am + k*64 + ty*4), ld4(Bl + k*64 + tx*4));
      fma4x4(acc, ld4(Ah + k*64 + ty*4), ld4(Br + k*64 + tx*4));
    }
  }
  float blv[4];
#pragma unroll
  for (int c = 0; c < 4; ++c) blv[c] = bl[j0 + tx*4 + c];
#pragma unroll
  for (int r = 0; r < 4; ++r) {
    const int row = i0 + ty*4 + r;
    if (row < N_NODES) {
      float o[4];
#pragma unroll
      for (int c = 0; c < 4; ++c) o[c] = fmaxf(acc[r][c] + blv[c], 0.f);
      *(float4*)(outp + (size_t)row*128 + j0 + tx*4) = make_float4(o[0],o[1],o[2],o[3]);
    }
  }
}

// -------------------- P = h3 @ Wc1[:, koff:koff+128]^T  (bf16 out) --------------------
__global__ __launch_bounds__(256) void k_p(const float* __restrict__ h3, const float* __restrict__ Wc1,
    int koff, bf16* __restrict__ P)
{
  __shared__ float As[16*64], Bs[16*64];
  const int i0 = blockIdx.x*64, j0 = blockIdx.y*64;
  const int t = threadIdx.x, tx = t & 15, ty = t >> 4;
  float acc[4][4] = {};
  for (int kt = 0; kt < 128; kt += 16) {
    __syncthreads();
    stageT(As, h3, i0, N_NODES, kt, 128);
    stageT(Bs, Wc1 + koff, j0, 1<<30, kt, 288);
    __syncthreads();
#pragma unroll
    for (int k = 0; k < 16; ++k)
      fma4x4(acc, ld4(As + k*64 + ty*4), ld4(Bs + k*64 + tx*4));
  }
#pragma unroll
  for (int r = 0; r < 4; ++r) {
    const int row = i0 + ty*4 + r;
    if (row < N_NODES) {
      union { bf16 b[4]; uint2 u; } pk;
#pragma unroll
      for (int c = 0; c < 4; ++c) pk.b[c] = __float2bfloat16(acc[r][c]);
      *(uint2*)(P + (size_t)row*256 + j0 + tx*4) = pk.u;
    }
  }
}

// -------------------- per-edge: out = Wc2 . relu(P1[s]+P2[d]+A3@ea+bc1) + bc2 --------------------
__global__ __launch_bounds__(256) void k_edge(const int* __restrict__ ei, const float* __restrict__ ea,
    const bf16* __restrict__ P1, const bf16* __restrict__ P2,
    const float* __restrict__ Wc1, const float* __restrict__ bc1,
    const float* __restrict__ Wc2, const float* __restrict__ bc2,
    float* __restrict__ outp)
{
  __shared__ float A3s[32][256];   // [k][j]
  __shared__ float eas[32][32];    // [edge_local][k]
  const int t = threadIdx.x;
  const int e0 = blockIdx.x * 32;
  {
    const float* wrow = Wc1 + (size_t)t*288 + 256;
#pragma unroll
    for (int kq = 0; kq < 8; ++kq) {
      float4 v = ld4(wrow + kq*4);
      A3s[kq*4+0][t] = v.x; A3s[kq*4+1][t] = v.y; A3s[kq*4+2][t] = v.z; A3s[kq*4+3][t] = v.w;
    }
  }
  {
    int eloc = t >> 3, kq = (t & 7) << 2;
    float4 v = ld4(ea + (size_t)(e0 + eloc)*32 + kq);
    *(float4*)&eas[eloc][kq] = v;
  }
  __syncthreads();
  const int w = t >> 6, L = t & 63;
  float bc1v[4], wc2v[4];
#pragma unroll
  for (int m = 0; m < 4; ++m) { bc1v[m] = bc1[L + 64*m]; wc2v[m] = Wc2[L + 64*m]; }
  const float bc2v = bc2[0];
  float acc[8][4] = {};
#pragma unroll 8
  for (int k = 0; k < 32; ++k) {
    float wv[4];
#pragma unroll
    for (int m = 0; m < 4; ++m) wv[m] = A3s[k][L + 64*m];
#pragma unroll
    for (int e8 = 0; e8 < 8; ++e8) {
      float ev = eas[w*8 + e8][k];
#pragma unroll
      for (int m = 0; m < 4; ++m) acc[e8][m] = fmaf(wv[m], ev, acc[e8][m]);
    }
  }
#pragma unroll
  for (int e8 = 0; e8 < 8; ++e8) {
    const int e = e0 + w*8 + e8;
    const int s = ei[e], d = ei[N_EDGES + e];
    float osum = 0.f;
#pragma unroll
    for (int m = 0; m < 4; ++m) {
      float p1 = __bfloat162float(P1[(size_t)s*256 + L + 64*m]);
      float p2 = __bfloat162float(P2[(size_t)d*256 + L + 64*m]);
      float hid = fmaxf(acc[e8][m] + p1 + p2 + bc1v[m], 0.f);
      osum = fmaf(wc2v[m], hid, osum);
    }
#pragma unroll
    for (int off = 32; off > 0; off >>= 1) osum += __shfl_xor(osum, off, 64);
    if (L == 0) outp[e] = osum + bc2v;
  }
}

extern "C" void kernel_launch(void* const* d_in, const int* in_sizes, int n_in,
                              void* d_out, int out_size, void* d_ws, size_t ws_size,
                              hipStream_t stream)
{
  const float* x   = (const float*)d_in[0];
  const float* h0  = (const float*)d_in[1];
  const int*   ei  = (const int*)d_in[2];
  const float* ea  = (const float*)d_in[3];
  const float* Wih = (const float*)d_in[4];
  const float* Whh = (const float*)d_in[5];
  const float* bih = (const float*)d_in[6];
  const float* bhh = (const float*)d_in[7];
  const float* Wl[3] = {(const float*)d_in[8],  (const float*)d_in[11], (const float*)d_in[14]};
  const float* bl[3] = {(const float*)d_in[9],  (const float*)d_in[12], (const float*)d_in[15]};
  const float* Wr[3] = {(const float*)d_in[10], (const float*)d_in[13], (const float*)d_in[16]};
  const float* Wc1 = (const float*)d_in[17];
  const float* bc1 = (const float*)d_in[18];
  const float* Wc2 = (const float*)d_in[19];
  const float* bc2 = (const float*)d_in[20];

  float* out  = (float*)d_out;
  float* hfin = (float*)d_out + N_EDGES;

  char* wp = (char*)d_ws;
  auto alloc = [&](size_t bytes) -> void* {
    void* p = (void*)wp; wp += (bytes + 255) & ~(size_t)255; return p;
  };
  float* bufA   = (float*)alloc((size_t)N_NODES*128*4);
  float* bufB   = (float*)alloc((size_t)N_NODES*128*4);
  float* bufM   = (float*)alloc((size_t)N_NODES*128*4);
  bf16*  P1     = (bf16*) alloc((size_t)N_NODES*256*2);
  bf16*  P2     = (bf16*) alloc((size_t)N_NODES*256*2);
  int*   counts = (int*)  alloc((size_t)N_NODES*4);
  int*   cursor = (int*)  alloc((size_t)N_NODES*4);
  int*   offs   = (int*)  alloc((size_t)(N_NODES+1)*4);
  int*   lst    = (int*)  alloc((size_t)N_EDGES*4);

  const dim3 b256(256);
  hipMemsetAsync(counts, 0, (size_t)N_NODES*4, stream);
  k_count<<<dim3((N_EDGES+255)/256), b256, 0, stream>>>(ei + N_EDGES, counts);
  k_scan<<<dim3(1), dim3(1024), 0, stream>>>(counts, offs, cursor);
  k_fill<<<dim3((N_EDGES+255)/256), b256, 0, stream>>>(ei, cursor, lst);

  const dim3 gemmGrid(1563, 2);
  k_gru<<<gemmGrid, b256, 0, stream>>>(x, h0, Wih, Whh, bih, bhh, bufA);

  const float* hcur = bufA;
  for (int l = 0; l < 3; ++l) {
    k_agg<<<dim3(25000), b256, 0, stream>>>(hcur, offs, lst, bufM);
    float* nxt = (l == 0) ? bufB : (l == 1) ? bufA : hfin;
    k_sage<<<gemmGrid, b256, 0, stream>>>(bufM, hcur, Wl[l], Wr[l], bl[l], nxt);
    hcur = nxt;
  }

  const dim3 pGrid(1563, 4);
  k_p<<<pGrid, b256, 0, stream>>>(hfin, Wc1, 0,   P1);
  k_p<<<pGrid, b256, 0, stream>>>(hfin, Wc1, 128, P2);

  k_edge<<<dim3(N_EDGES/32), b256, 0, stream>>>(ei, ea, P1, P2, Wc1, bc1, Wc2, bc2, out);
}

// Round 2
// 977.789 us; speedup vs baseline: 1.5770x; 1.5770x over previous
//
#include <hip/hip_runtime.h>
#include <hip/hip_bf16.h>

#define N_NODES 100000
#define N_EDGES 600000

typedef unsigned short u16;
typedef unsigned int u32;
typedef short bf16x8 __attribute__((ext_vector_type(8)));
typedef float f32x4 __attribute__((ext_vector_type(4)));

__device__ __forceinline__ float4 ld4(const float* p){ return *(const float4*)p; }
__device__ __forceinline__ float sigm(float v){ return 1.0f/(1.0f + __expf(-v)); }
__device__ __forceinline__ float tanh_fast(float v){
  float e = __expf(-2.0f*fabsf(v));
  float r = (1.0f - e)/(1.0f + e);
  return copysignf(r, v);
}
// f32 -> bf16 bits, RNE
__device__ __forceinline__ u32 bfr(float f){
  u32 u = __float_as_uint(f);
  return (u + 0x7FFFu + ((u>>16)&1u)) >> 16;
}
__device__ __forceinline__ uint4 pack8(float4 a, float4 b){
  uint4 r;
  r.x = bfr(a.x) | (bfr(a.y)<<16);
  r.y = bfr(a.z) | (bfr(a.w)<<16);
  r.z = bfr(b.x) | (bfr(b.y)<<16);
  r.w = bfr(b.z) | (bfr(b.w)<<16);
  return r;
}
__device__ __forceinline__ void unp8(uint4 u, float* f){
  f[0]=__uint_as_float(u.x<<16); f[1]=__uint_as_float(u.x & 0xFFFF0000u);
  f[2]=__uint_as_float(u.y<<16); f[3]=__uint_as_float(u.y & 0xFFFF0000u);
  f[4]=__uint_as_float(u.z<<16); f[5]=__uint_as_float(u.z & 0xFFFF0000u);
  f[6]=__uint_as_float(u.w<<16); f[7]=__uint_as_float(u.w & 0xFFFF0000u);
}
__device__ __forceinline__ void gload16(const void* g, void* l){
  __builtin_amdgcn_global_load_lds((__attribute__((address_space(1))) void*)(g),
                                   (__attribute__((address_space(3))) void*)(l), 16, 0, 0);
}

// ==================== weight pack kernels (fragment layout) ====================
// Layout: Wp[nblk][kstep][grp8][lane64][8 bf16]; col = nblk*128+grp*16+(lane&15),
// k = kstep*32 + (lane>>4)*8 + j  -> B frag for mfma_f32_16x16x32_bf16.

__global__ void k_pack_gru(const float* __restrict__ Wih, const float* __restrict__ Whh,
                           u16* __restrict__ Wg){
  int c = blockIdx.x*256 + threadIdx.x;        // 16384
  int lane = c&63, grp = (c>>6)&7, ks = (c>>9)&7, nb = c>>12;
  int col = nb*128 + grp*16 + (lane&15);
  int kg = ks*32 + ((lane>>4)<<3);
  const float* src = nullptr;
  bool xs = kg < 128;
  if (col < 256)      src = xs ? Wih + (size_t)col*128 + kg : Whh + (size_t)col*128 + kg-128;
  else if (col < 384) src = xs ? Wih + (size_t)col*128 + kg : nullptr;
  else                src = xs ? nullptr : Whh + (size_t)(col-128)*128 + kg-128;
  float4 v0 = {0,0,0,0}, v1 = {0,0,0,0};
  if (src){ v0 = ld4(src); v1 = ld4(src+4); }
  ((uint4*)Wg)[c] = pack8(v0, v1);
}

__global__ void k_pack_sage(const float* __restrict__ Wl, const float* __restrict__ Wr,
                            u16* __restrict__ Wg){
  int c = blockIdx.x*256 + threadIdx.x;        // 4096
  int lane = c&63, grp = (c>>6)&7, ks = c>>9;
  int col = grp*16 + (lane&15);
  int kg = ks*32 + ((lane>>4)<<3);
  const float* src = (kg < 128) ? Wl + (size_t)col*128 + kg : Wr + (size_t)col*128 + kg-128;
  ((uint4*)Wg)[c] = pack8(ld4(src), ld4(src+4));
}

__global__ void k_pack_p(const float* __restrict__ Wc1, u16* __restrict__ Wg){
  int c = blockIdx.x*256 + threadIdx.x;        // 8192
  int lane = c&63, grp = (c>>6)&7, ks = (c>>9)&3, nb = c>>11;
  int col = nb*128 + grp*16 + (lane&15);
  int kg = ks*32 + ((lane>>4)<<3);
  const float* src = (col < 256) ? Wc1 + (size_t)col*288 + kg
                                 : Wc1 + (size_t)(col-256)*288 + 128 + kg;
  ((uint4*)Wg)[c] = pack8(ld4(src), ld4(src+4));
}

// ==================== MFMA GEMM: C = [A1|A2] @ Wp^T ====================
// 128x128 block tile, 4 waves, wave tile 64x64 (4x4 frags of 16x16x32).
// A1/A2: f32 [M,128] each (A2 used for kstep>=4). EPI 0: bf16 store; 1: relu(+bias) f32.
template<int NK, int EPI, int NOUT>
__global__ __launch_bounds__(256) void k_mm(
    const float* __restrict__ A1, const float* __restrict__ A2,
    const u16* __restrict__ Wp, const float* __restrict__ bias,
    float* __restrict__ outF, u16* __restrict__ outB)
{
  __shared__ __align__(16) char smem[16384];   // A: [0,8K) B: [8K,16K)
  const int t = threadIdx.x, L = t & 63, w = t >> 6;
  const int mw = w >> 1, nw = w & 1;
  const int i0 = blockIdx.x * 128, by = blockIdx.y;
  const f32x4 z4 = {0.f,0.f,0.f,0.f};
  f32x4 acc[4][4];
#pragma unroll
  for (int i=0;i<4;++i)
#pragma unroll
  for (int j=0;j<4;++j) acc[i][j] = z4;

  for (int ks = 0; ks < NK; ++ks){
    if (ks) __syncthreads();
    // ---- B stage: 8KB via global_load_lds (2 x 1KB chunks per wave)
    {
      const u16* src = Wp + ((size_t)(by*NK + ks) << 12);
#pragma unroll
      for (int c = 0; c < 2; ++c){
        int cw = w*2 + c;
        gload16(src + cw*512 + L*8, smem + 8192 + cw*1024);
      }
    }
    // ---- A stage: 128 rows x 32 k, f32 -> bf16, fragment layout
#pragma unroll
    for (int sh = 0; sh < 2; ++sh){
      int s = t + sh*256;
      int l2 = s & 63;
      int row = i0 + ((s>>6)<<4) + (l2 & 15);
      int kg = ks*32 + ((l2>>4)<<3);
      const float* src;
      if (ks < 4) src = A1 + (size_t)row*128 + kg;
      else        src = A2 + (size_t)row*128 + (kg - 128);
      float4 v0 = {0,0,0,0}, v1 = {0,0,0,0};
      if (row < N_NODES){ v0 = ld4(src); v1 = ld4(src+4); }
      *(uint4*)(smem + s*16) = pack8(v0, v1);
    }
    __syncthreads();
    // ---- compute
    bf16x8 a[4], b[4];
#pragma unroll
    for (int i = 0; i < 4; ++i) a[i] = *(const bf16x8*)(smem + ((mw*4+i)*64 + L)*16);
#pragma unroll
    for (int j = 0; j < 4; ++j) b[j] = *(const bf16x8*)(smem + 8192 + ((nw*4+j)*64 + L)*16);
#pragma unroll
    for (int i = 0; i < 4; ++i)
#pragma unroll
      for (int j = 0; j < 4; ++j)
        acc[i][j] = __builtin_amdgcn_mfma_f32_16x16x32_bf16(a[i], b[j], acc[i][j], 0, 0, 0);
  }
  // ---- epilogue: D frag: col=lane&15, row=(lane>>4)*4+q
  const int r4 = (L>>4)*4, cL = L&15;
#pragma unroll
  for (int i = 0; i < 4; ++i){
    int rbase = i0 + mw*64 + i*16 + r4;
#pragma unroll
    for (int j = 0; j < 4; ++j){
      int col = by*128 + nw*64 + j*16 + cL;
#pragma unroll
      for (int q = 0; q < 4; ++q){
        int row = rbase + q;
        if (row < N_NODES){
          float v = acc[i][j][q];
          if (EPI == 1) outF[(size_t)row*NOUT + col] = fmaxf(v + bias[col], 0.f);
          else          outB[(size_t)row*NOUT + col] = (u16)bfr(v);
        }
      }
    }
  }
}

// ==================== GRU gate fusion ====================
// G bf16 [N,512] = [r_pre | z_pre | i_n | h_n] (no biases)
__global__ __launch_bounds__(256) void k_gates(const u16* __restrict__ G,
    const float* __restrict__ h0, const float* __restrict__ bih,
    const float* __restrict__ bhh, float* __restrict__ hout)
{
  int idx = blockIdx.x*256 + threadIdx.x;      // 100000*16 exact
  int row = idx >> 4, c8 = (idx & 15) << 3;
  const u16* g = G + (size_t)row*512;
  float gr[8], gz[8], gn[8], gh[8];
  unp8(*(const uint4*)(g + c8),       gr);
  unp8(*(const uint4*)(g + 128 + c8), gz);
  unp8(*(const uint4*)(g + 256 + c8), gn);
  unp8(*(const uint4*)(g + 384 + c8), gh);
  float4 ha = ld4(h0 + (size_t)row*128 + c8), hb = ld4(h0 + (size_t)row*128 + c8 + 4);
  float hv[8] = {ha.x,ha.y,ha.z,ha.w,hb.x,hb.y,hb.z,hb.w};
  float o[8];
#pragma unroll
  for (int c = 0; c < 8; ++c){
    float br = bih[c8+c] + bhh[c8+c];
    float bz = bih[128+c8+c] + bhh[128+c8+c];
    float rr = sigm(gr[c] + br);
    float zz = sigm(gz[c] + bz);
    float nn = tanh_fast(gn[c] + bih[256+c8+c] + rr*(gh[c] + bhh[256+c8+c]));
    o[c] = (1.f - zz)*nn + zz*hv[c];
  }
  float* op = hout + (size_t)row*128 + c8;
  *(float4*)op       = make_float4(o[0],o[1],o[2],o[3]);
  *(float4*)(op + 4) = make_float4(o[4],o[5],o[6],o[7]);
}

// ==================== CSR build ====================
__global__ void k_count(const int* __restrict__ dst, int* __restrict__ counts){
  int e = blockIdx.x*256 + threadIdx.x;
  if (e < N_EDGES) atomicAdd(&counts[dst[e]], 1);
}

__global__ __launch_bounds__(1024) void k_scan(const int* __restrict__ counts,
    int* __restrict__ offs, int* __restrict__ cursor)
{
  __shared__ int wsum[16];
  __shared__ int cbase;
  const int t = threadIdx.x, lane = t & 63, w = t >> 6;
  if (t == 0) cbase = 0;
  __syncthreads();
  for (int base = 0; base < N_NODES; base += 1024) {
    int i = base + t;
    int v = (i < N_NODES) ? counts[i] : 0;
    int s = v;
#pragma unroll
    for (int d = 1; d < 64; d <<= 1) {
      int u = __shfl_up(s, d, 64);
      if (lane >= d) s += u;
    }
    if (lane == 63) wsum[w] = s;
    __syncthreads();
    int add0 = cbase;
    if (w == 0) {
      int ws = (lane < 16) ? wsum[lane] : 0;
#pragma unroll
      for (int d = 1; d < 16; d <<= 1) {
        int u = __shfl_up(ws, d, 64);
        if (lane >= d) ws += u;
      }
      if (lane < 16) wsum[lane] = ws;
    }
    __syncthreads();
    int wbase = (w == 0) ? 0 : wsum[w-1];
    int excl = add0 + wbase + (s - v);
    if (i < N_NODES) { offs[i] = excl; cursor[i] = excl; }
    __syncthreads();
    if (t == 0) cbase += wsum[15];
    __syncthreads();
  }
  if (t == 0) offs[N_NODES] = cbase;
}

__global__ void k_fill(const int* __restrict__ ei, int* __restrict__ cursor, int* __restrict__ lst){
  int e = blockIdx.x*256 + threadIdx.x;
  if (e < N_EDGES){
    int d = ei[N_EDGES + e];
    int slot = atomicAdd(&cursor[d], 1);
    lst[slot] = ei[e];
  }
}

// ==================== mean aggregation: one wave per node ====================
__global__ __launch_bounds__(256) void k_agg(const float* __restrict__ h,
    const int* __restrict__ offs, const int* __restrict__ lst, float* __restrict__ mean)
{
  const int node = blockIdx.x*4 + (threadIdx.x >> 6);
  if (node >= N_NODES) return;
  const int lane = threadIdx.x & 63;
  const int beg = offs[node], end = offs[node+1];
  float ax = 0.f, ay = 0.f;
  const float2* hp = (const float2*)h;
  for (int e = beg; e < end; ++e) {
    int s = lst[e];
    float2 v = hp[(size_t)s*64 + lane];
    ax += v.x; ay += v.y;
  }
  float inv = 1.f / fmaxf((float)(end - beg), 1.f);
  float2 o; o.x = ax*inv; o.y = ay*inv;
  ((float2*)mean)[(size_t)node*64 + lane] = o;
}

// ==================== per-edge classifier ====================
// P bf16 [N,512] = [P1 | P2]; out = Wc2 . relu(P1[s]+P2[d]+A3@ea+bc1) + bc2
__global__ __launch_bounds__(256) void k_edge(const int* __restrict__ ei, const float* __restrict__ ea,
    const u16* __restrict__ P,
    const float* __restrict__ Wc1, const float* __restrict__ bc1,
    const float* __restrict__ Wc2, const float* __restrict__ bc2,
    float* __restrict__ outp)
{
  __shared__ float A3s[32][256];   // [k][j]
  __shared__ float eas[32][32];    // [edge_local][k]
  const int t = threadIdx.x;
  const int e0 = blockIdx.x * 32;
  {
    const float* wrow = Wc1 + (size_t)t*288 + 256;
#pragma unroll
    for (int kq = 0; kq < 8; ++kq) {
      float4 v = ld4(wrow + kq*4);
      A3s[kq*4+0][t] = v.x; A3s[kq*4+1][t] = v.y; A3s[kq*4+2][t] = v.z; A3s[kq*4+3][t] = v.w;
    }
  }
  {
    int eloc = t >> 3, kq = (t & 7) << 2;
    float4 v = ld4(ea + (size_t)(e0 + eloc)*32 + kq);
    *(float4*)&eas[eloc][kq] = v;
  }
  __syncthreads();
  const int w = t >> 6, L = t & 63;
  float bc1v[4], wc2v[4];
#pragma unroll
  for (int m = 0; m < 4; ++m) { bc1v[m] = bc1[L + 64*m]; wc2v[m] = Wc2[L + 64*m]; }
  const float bc2v = bc2[0];
  float acc[8][4] = {};
#pragma unroll 8
  for (int k = 0; k < 32; ++k) {
    float wv[4];
#pragma unroll
    for (int m = 0; m < 4; ++m) wv[m] = A3s[k][L + 64*m];
#pragma unroll
    for (int e8 = 0; e8 < 8; ++e8) {
      float ev = eas[w*8 + e8][k];
#pragma unroll
      for (int m = 0; m < 4; ++m) acc[e8][m] = fmaf(wv[m], ev, acc[e8][m]);
    }
  }
#pragma unroll
  for (int e8 = 0; e8 < 8; ++e8) {
    const int e = e0 + w*8 + e8;
    const int s = ei[e], d = ei[N_EDGES + e];
    const u16* p1 = P + (size_t)s*512;
    const u16* p2 = P + (size_t)d*512 + 256;
    float osum = 0.f;
#pragma unroll
    for (int m = 0; m < 4; ++m) {
      float v1 = __uint_as_float(((u32)p1[L + 64*m])<<16);
      float v2 = __uint_as_float(((u32)p2[L + 64*m])<<16);
      float hid = fmaxf(acc[e8][m] + v1 + v2 + bc1v[m], 0.f);
      osum = fmaf(wc2v[m], hid, osum);
    }
#pragma unroll
    for (int off = 32; off > 0; off >>= 1) osum += __shfl_xor(osum, off, 64);
    if (L == 0) outp[e] = osum + bc2v;
  }
}

extern "C" void kernel_launch(void* const* d_in, const int* in_sizes, int n_in,
                              void* d_out, int out_size, void* d_ws, size_t ws_size,
                              hipStream_t stream)
{
  const float* x   = (const float*)d_in[0];
  const float* h0  = (const float*)d_in[1];
  const int*   ei  = (const int*)d_in[2];
  const float* ea  = (const float*)d_in[3];
  const float* Wih = (const float*)d_in[4];
  const float* Whh = (const float*)d_in[5];
  const float* bih = (const float*)d_in[6];
  const float* bhh = (const float*)d_in[7];
  const float* Wl[3] = {(const float*)d_in[8],  (const float*)d_in[11], (const float*)d_in[14]};
  const float* bl[3] = {(const float*)d_in[9],  (const float*)d_in[12], (const float*)d_in[15]};
  const float* Wr[3] = {(const float*)d_in[10], (const float*)d_in[13], (const float*)d_in[16]};
  const float* Wc1 = (const float*)d_in[17];
  const float* bc1 = (const float*)d_in[18];
  const float* Wc2 = (const float*)d_in[19];
  const float* bc2 = (const float*)d_in[20];

  float* out  = (float*)d_out;
  float* hfin = (float*)d_out + N_EDGES;

  char* wp = (char*)d_ws;
  auto alloc = [&](size_t bytes) -> void* {
    void* p = (void*)wp; wp += (bytes + 255) & ~(size_t)255; return p;
  };
  float* bufA  = (float*)alloc((size_t)N_NODES*128*4);
  float* bufB  = (float*)alloc((size_t)N_NODES*128*4);
  float* bufM  = (float*)alloc((size_t)N_NODES*128*4);
  u16*   GP    = (u16*)  alloc((size_t)N_NODES*512*2);   // G (GRU), then reused as P
  u16*   Wg_g  = (u16*)  alloc((size_t)16384*16);
  u16*   Wg_s0 = (u16*)  alloc((size_t)4096*16);
  u16*   Wg_s1 = (u16*)  alloc((size_t)4096*16);
  u16*   Wg_s2 = (u16*)  alloc((size_t)4096*16);
  u16*   Wg_p  = (u16*)  alloc((size_t)8192*16);
  int*   counts= (int*)  alloc((size_t)N_NODES*4);
  int*   cursor= (int*)  alloc((size_t)N_NODES*4);
  int*   offs  = (int*)  alloc((size_t)(N_NODES+1)*4);
  int*   lst   = (int*)  alloc((size_t)N_EDGES*4);
  u16*   Wg_sl[3] = {Wg_s0, Wg_s1, Wg_s2};

  const dim3 b256(256);

  // CSR + weight packs (cheap, up front)
  hipMemsetAsync(counts, 0, (size_t)N_NODES*4, stream);
  k_count<<<dim3((N_EDGES+255)/256), b256, 0, stream>>>(ei + N_EDGES, counts);
  k_scan<<<dim3(1), dim3(1024), 0, stream>>>(counts, offs, cursor);
  k_fill<<<dim3((N_EDGES+255)/256), b256, 0, stream>>>(ei, cursor, lst);
  k_pack_gru<<<dim3(64), b256, 0, stream>>>(Wih, Whh, Wg_g);
  for (int l = 0; l < 3; ++l)
    k_pack_sage<<<dim3(16), b256, 0, stream>>>(Wl[l], Wr[l], Wg_sl[l]);
  k_pack_p<<<dim3(32), b256, 0, stream>>>(Wc1, Wg_p);

  // GRU: G = [x|h0] @ Wcat^T (bf16), then gates
  k_mm<8,0,512><<<dim3(782,4), b256, 0, stream>>>(x, h0, Wg_g, nullptr, nullptr, GP);
  k_gates<<<dim3(6250), b256, 0, stream>>>(GP, h0, bih, bhh, bufA);

  // 3x SAGE
  const float* hcur = bufA;
  for (int l = 0; l < 3; ++l) {
    k_agg<<<dim3(25000), b256, 0, stream>>>(hcur, offs, lst, bufM);
    float* nxt = (l == 0) ? bufB : (l == 1) ? bufA : hfin;
    k_mm<8,1,128><<<dim3(782,1), b256, 0, stream>>>(bufM, hcur, Wg_sl[l], bl[l], nxt, nullptr);
    hcur = nxt;
  }

  // P = h3 @ [A1;A2]^T (bf16) ; then per-edge classifier
  k_mm<4,0,512><<<dim3(782,4), b256, 0, stream>>>(hfin, hfin, Wg_p, nullptr, nullptr, GP);
  k_edge<<<dim3(N_EDGES/32), b256, 0, stream>>>(ei, ea, GP, Wc1, bc1, Wc2, bc2, out);
}

// Round 3
// 661.995 us; speedup vs baseline: 2.3294x; 1.4770x over previous
//
#include <hip/hip_runtime.h>
#include <hip/hip_bf16.h>

#define N_NODES 100000
#define NPAD    100096
#define N_EDGES 600000

typedef unsigned short u16;
typedef unsigned int u32;
typedef short bf16x8 __attribute__((ext_vector_type(8)));
typedef float f32x4 __attribute__((ext_vector_type(4)));

__device__ __forceinline__ float4 ld4(const float* p){ return *(const float4*)p; }
__device__ __forceinline__ float sigm(float v){ return 1.0f/(1.0f + __expf(-v)); }
__device__ __forceinline__ float tanh_fast(float v){
  float e = __expf(-2.0f*fabsf(v));
  float r = (1.0f - e)/(1.0f + e);
  return copysignf(r, v);
}
// f32 -> bf16 bits, RNE
__device__ __forceinline__ u32 bfr(float f){
  u32 u = __float_as_uint(f);
  return (u + 0x7FFFu + ((u>>16)&1u)) >> 16;
}
__device__ __forceinline__ float b2f(u16 b){ return __uint_as_float(((u32)b)<<16); }
__device__ __forceinline__ uint4 pack8(float4 a, float4 b){
  uint4 r;
  r.x = bfr(a.x) | (bfr(a.y)<<16);
  r.y = bfr(a.z) | (bfr(a.w)<<16);
  r.z = bfr(b.x) | (bfr(b.y)<<16);
  r.w = bfr(b.z) | (bfr(b.w)<<16);
  return r;
}
__device__ __forceinline__ void unp8(uint4 u, float* f){
  f[0]=__uint_as_float(u.x<<16); f[1]=__uint_as_float(u.x & 0xFFFF0000u);
  f[2]=__uint_as_float(u.y<<16); f[3]=__uint_as_float(u.y & 0xFFFF0000u);
  f[4]=__uint_as_float(u.z<<16); f[5]=__uint_as_float(u.z & 0xFFFF0000u);
  f[6]=__uint_as_float(u.w<<16); f[7]=__uint_as_float(u.w & 0xFFFF0000u);
}
__device__ __forceinline__ void gload16(const void* g, void* l){
  __builtin_amdgcn_global_load_lds((__attribute__((address_space(1))) void*)(g),
                                   (__attribute__((address_space(3))) void*)(l), 16, 0, 0);
}

// ==================== f32 -> bf16 cast with row padding ====================
__global__ __launch_bounds__(256) void k_cast(const float* __restrict__ src, u16* __restrict__ dst){
  int idx = blockIdx.x*256 + threadIdx.x;      // NPAD*16 exact
  int row = idx >> 4, c8 = (idx & 15) << 3;
  float4 v0 = {0,0,0,0}, v1 = {0,0,0,0};
  if (row < N_NODES){
    v0 = ld4(src + (size_t)row*128 + c8);
    v1 = ld4(src + (size_t)row*128 + c8 + 4);
  }
  *(uint4*)(dst + (size_t)row*128 + c8) = pack8(v0, v1);
}

// ==================== weight pack kernels (MFMA B-fragment layout) ====================
__global__ void k_pack_gru(const float* __restrict__ Wih, const float* __restrict__ Whh,
                           u16* __restrict__ Wg){
  int c = blockIdx.x*256 + threadIdx.x;        // 16384
  int lane = c&63, grp = (c>>6)&7, ks = (c>>9)&7, nb = c>>12;
  int col = nb*128 + grp*16 + (lane&15);
  int kg = ks*32 + ((lane>>4)<<3);
  const float* src = nullptr;
  bool xs = kg < 128;
  if (col < 256)      src = xs ? Wih + (size_t)col*128 + kg : Whh + (size_t)col*128 + kg-128;
  else if (col < 384) src = xs ? Wih + (size_t)col*128 + kg : nullptr;
  else                src = xs ? nullptr : Whh + (size_t)(col-128)*128 + kg-128;
  float4 v0 = {0,0,0,0}, v1 = {0,0,0,0};
  if (src){ v0 = ld4(src); v1 = ld4(src+4); }
  ((uint4*)Wg)[c] = pack8(v0, v1);
}

__global__ void k_pack_sage(const float* __restrict__ Wl, const float* __restrict__ Wr,
                            u16* __restrict__ Wg){
  int c = blockIdx.x*256 + threadIdx.x;        // 4096
  int lane = c&63, grp = (c>>6)&7, ks = c>>9;
  int col = grp*16 + (lane&15);
  int kg = ks*32 + ((lane>>4)<<3);
  const float* src = (kg < 128) ? Wl + (size_t)col*128 + kg : Wr + (size_t)col*128 + kg-128;
  ((uint4*)Wg)[c] = pack8(ld4(src), ld4(src+4));
}

__global__ void k_pack_p(const float* __restrict__ Wc1, u16* __restrict__ Wg){
  int c = blockIdx.x*256 + threadIdx.x;        // 8192
  int lane = c&63, grp = (c>>6)&7, ks = (c>>9)&3, nb = c>>11;
  int col = nb*128 + grp*16 + (lane&15);
  int kg = ks*32 + ((lane>>4)<<3);
  const float* src = (col < 256) ? Wc1 + (size_t)col*288 + kg
                                 : Wc1 + (size_t)(col-256)*288 + 128 + kg;
  ((uint4*)Wg)[c] = pack8(ld4(src), ld4(src+4));
}

// ==================== MFMA GEMM: C = [A1|A2] @ Wp^T (A bf16, padded rows) ====================
// 128x128 tile, 4 waves, wave tile 64x64. EPI 0: bf16 [NPAD,512]; 1: relu+bias bf16 [NPAD,128];
// 2: relu+bias bf16 + f32 (guarded) stores.
template<int NK, int EPI, int NOUT>
__global__ __launch_bounds__(256) void k_mm(
    const u16* __restrict__ A1, const u16* __restrict__ A2,
    const u16* __restrict__ Wp, const float* __restrict__ bias,
    float* __restrict__ outF, u16* __restrict__ outB)
{
  __shared__ __align__(16) char smem[16384];   // A: [0,8K) B: [8K,16K)
  const int t = threadIdx.x, L = t & 63, w = t >> 6;
  const int mw = w >> 1, nw = w & 1;
  const int i0 = blockIdx.x * 128, by = blockIdx.y;
  const f32x4 z4 = {0.f,0.f,0.f,0.f};
  f32x4 acc[4][4];
#pragma unroll
  for (int i=0;i<4;++i)
#pragma unroll
  for (int j=0;j<4;++j) acc[i][j] = z4;

  for (int ks = 0; ks < NK; ++ks){
    if (ks) __syncthreads();
    // B stage: 8KB via global_load_lds
    {
      const u16* src = Wp + ((size_t)(by*NK + ks) << 12);
#pragma unroll
      for (int c = 0; c < 2; ++c){
        int cw = w*2 + c;
        gload16(src + cw*512 + L*8, smem + 8192 + cw*1024);
      }
    }
    // A stage: 128 rows x 32 k bf16, fragment layout, pure DMA
#pragma unroll
    for (int sh = 0; sh < 2; ++sh){
      int s = t + sh*256;
      int l2 = s & 63;
      int row = i0 + ((s>>6)<<4) + (l2 & 15);
      int kg = ks*32 + ((l2>>4)<<3);
      const u16* src = (ks < 4) ? A1 + (size_t)row*128 + kg
                                : A2 + (size_t)row*128 + kg - 128;
      gload16(src, smem + s*16);
    }
    __syncthreads();
    bf16x8 a[4], b[4];
#pragma unroll
    for (int i = 0; i < 4; ++i) a[i] = *(const bf16x8*)(smem + ((mw*4+i)*64 + L)*16);
#pragma unroll
    for (int j = 0; j < 4; ++j) b[j] = *(const bf16x8*)(smem + 8192 + ((nw*4+j)*64 + L)*16);
#pragma unroll
    for (int i = 0; i < 4; ++i)
#pragma unroll
      for (int j = 0; j < 4; ++j)
        acc[i][j] = __builtin_amdgcn_mfma_f32_16x16x32_bf16(a[i], b[j], acc[i][j], 0, 0, 0);
  }
  const int r4 = (L>>4)*4, cL = L&15;
#pragma unroll
  for (int i = 0; i < 4; ++i){
    int rbase = i0 + mw*64 + i*16 + r4;
#pragma unroll
    for (int j = 0; j < 4; ++j){
      int col = by*128 + nw*64 + j*16 + cL;
#pragma unroll
      for (int q = 0; q < 4; ++q){
        int row = rbase + q;
        float v = acc[i][j][q];
        if (EPI == 0){
          outB[(size_t)row*NOUT + col] = (u16)bfr(v);
        } else {
          float rv = fmaxf(v + bias[col], 0.f);
          outB[(size_t)row*NOUT + col] = (u16)bfr(rv);
          if (EPI == 2 && row < N_NODES) outF[(size_t)row*NOUT + col] = rv;
        }
      }
    }
  }
}

// ==================== GRU gate fusion (bf16 G in, bf16 h out) ====================
__global__ __launch_bounds__(256) void k_gates(const u16* __restrict__ G,
    const float* __restrict__ h0, const float* __restrict__ bih,
    const float* __restrict__ bhh, u16* __restrict__ hout)
{
  int idx = blockIdx.x*256 + threadIdx.x;      // 100000*16 exact
  int row = idx >> 4, c8 = (idx & 15) << 3;
  const u16* g = G + (size_t)row*512;
  float gr[8], gz[8], gn[8], gh[8];
  unp8(*(const uint4*)(g + c8),       gr);
  unp8(*(const uint4*)(g + 128 + c8), gz);
  unp8(*(const uint4*)(g + 256 + c8), gn);
  unp8(*(const uint4*)(g + 384 + c8), gh);
  float4 ha = ld4(h0 + (size_t)row*128 + c8), hb = ld4(h0 + (size_t)row*128 + c8 + 4);
  float hv[8] = {ha.x,ha.y,ha.z,ha.w,hb.x,hb.y,hb.z,hb.w};
  float4 o0, o1; float o[8];
#pragma unroll
  for (int c = 0; c < 8; ++c){
    float br = bih[c8+c] + bhh[c8+c];
    float bz = bih[128+c8+c] + bhh[128+c8+c];
    float rr = sigm(gr[c] + br);
    float zz = sigm(gz[c] + bz);
    float nn = tanh_fast(gn[c] + bih[256+c8+c] + rr*(gh[c] + bhh[256+c8+c]));
    o[c] = (1.f - zz)*nn + zz*hv[c];
  }
  o0 = make_float4(o[0],o[1],o[2],o[3]);
  o1 = make_float4(o[4],o[5],o[6],o[7]);
  *(uint4*)(hout + (size_t)row*128 + c8) = pack8(o0, o1);
}

// ==================== CSR build (src, dst, eid per slot) ====================
__global__ void k_count(const int* __restrict__ dst, int* __restrict__ counts){
  int e = blockIdx.x*256 + threadIdx.x;
  if (e < N_EDGES) atomicAdd(&counts[dst[e]], 1);
}

__global__ __launch_bounds__(1024) void k_scan(const int* __restrict__ counts,
    int* __restrict__ offs, int* __restrict__ cursor)
{
  __shared__ int wsum[16];
  __shared__ int cbase;
  const int t = threadIdx.x, lane = t & 63, w = t >> 6;
  if (t == 0) cbase = 0;
  __syncthreads();
  for (int base = 0; base < N_NODES; base += 1024) {
    int i = base + t;
    int v = (i < N_NODES) ? counts[i] : 0;
    int s = v;
#pragma unroll
    for (int d = 1; d < 64; d <<= 1) {
      int u = __shfl_up(s, d, 64);
      if (lane >= d) s += u;
    }
    if (lane == 63) wsum[w] = s;
    __syncthreads();
    int add0 = cbase;
    if (w == 0) {
      int ws = (lane < 16) ? wsum[lane] : 0;
#pragma unroll
      for (int d = 1; d < 16; d <<= 1) {
        int u = __shfl_up(ws, d, 64);
        if (lane >= d) ws += u;
      }
      if (lane < 16) wsum[lane] = ws;
    }
    __syncthreads();
    int wbase = (w == 0) ? 0 : wsum[w-1];
    int excl = add0 + wbase + (s - v);
    if (i < N_NODES) { offs[i] = excl; cursor[i] = excl; }
    __syncthreads();
    if (t == 0) cbase += wsum[15];
    __syncthreads();
  }
  if (t == 0) offs[N_NODES] = cbase;
}

__global__ void k_fill(const int* __restrict__ ei, int* __restrict__ cursor,
                       int* __restrict__ lstS, int* __restrict__ lstD, int* __restrict__ lstE){
  int e = blockIdx.x*256 + threadIdx.x;
  if (e < N_EDGES){
    int s = ei[e], d = ei[N_EDGES + e];
    int slot = atomicAdd(&cursor[d], 1);
    lstS[slot] = s; lstD[slot] = d; lstE[slot] = e;
  }
}

// ==================== mean aggregation (bf16): 32 lanes per node ====================
__global__ __launch_bounds__(256) void k_agg(const u16* __restrict__ hb,
    const int* __restrict__ offs, const int* __restrict__ lst, u16* __restrict__ meanb)
{
  const int node = blockIdx.x*8 + (threadIdx.x >> 5);
  if (node >= NPAD) return;
  const int l32 = threadIdx.x & 31;
  int beg = 0, end = 0;
  if (node < N_NODES){ beg = offs[node]; end = offs[node+1]; }
  float a0=0.f, a1=0.f, a2=0.f, a3=0.f;
  for (int p = beg; p < end; ++p){
    int s = lst[p];
    uint2 v = *(const uint2*)(hb + (size_t)s*128 + l32*4);
    a0 += __uint_as_float(v.x<<16); a1 += __uint_as_float(v.x & 0xFFFF0000u);
    a2 += __uint_as_float(v.y<<16); a3 += __uint_as_float(v.y & 0xFFFF0000u);
  }
  float inv = 1.f / fmaxf((float)(end - beg), 1.f);
  uint2 o;
  o.x = bfr(a0*inv) | (bfr(a1*inv)<<16);
  o.y = bfr(a2*inv) | (bfr(a3*inv)<<16);
  *(uint2*)(meanb + (size_t)node*128 + l32*4) = o;
}

// ==================== per-edge classifier: MFMA + CSR-ordered gathers ====================
__global__ __launch_bounds__(256) void k_edge(
    const int* __restrict__ lstS, const int* __restrict__ lstD, const int* __restrict__ lstE,
    const float* __restrict__ ea, const u16* __restrict__ P,
    const float* __restrict__ Wc1, const float* __restrict__ bc1,
    const float* __restrict__ Wc2, const float* __restrict__ bc2,
    float* __restrict__ outp)
{
  __shared__ __align__(16) u16 Bf[16*64*8];    // 16KB: A3 as B-frags
  const int t = threadIdx.x, L = t & 63, w = t >> 6;
#pragma unroll
  for (int i = 0; i < 4; ++i){
    int c = t + i*256;
    int lc = c & 63;
    int j = ((c>>6)<<4) + (lc & 15), k0 = (lc >> 4) << 3;
    const float* src = Wc1 + (size_t)j*288 + 256 + k0;
    *(uint4*)(Bf + c*8) = pack8(ld4(src), ld4(src+4));
  }
  float bc1v[16], wc2v[16];
  const int cL = L & 15;
#pragma unroll
  for (int jb = 0; jb < 16; ++jb){
    bc1v[jb] = bc1[jb*16 + cL];
    wc2v[jb] = Wc2[jb*16 + cL];
  }
  const float bc2v = bc2[0];
  const int pos0 = blockIdx.x*64 + w*16;
  // ea A-frag (row = lane&15 edge, k = (lane>>4)*8)
  bf16x8 afrag;
  {
    int e = lstE[pos0 + cL];
    const float* src = ea + (size_t)e*32 + ((L >> 4) << 3);
    uint4 pk = pack8(ld4(src), ld4(src+4));
    afrag = *(bf16x8*)&pk;
  }
  int sQ[4], dQ[4], eQ[4];
#pragma unroll
  for (int q = 0; q < 4; ++q){
    int pos = pos0 + (L>>4)*4 + q;
    sQ[q] = lstS[pos]; dQ[q] = lstD[pos]; eQ[q] = lstE[pos];
  }
  __syncthreads();
  float osum[4] = {0.f,0.f,0.f,0.f};
#pragma unroll
  for (int jb = 0; jb < 16; ++jb){
    f32x4 acc = {0.f,0.f,0.f,0.f};
    bf16x8 b = *(const bf16x8*)(Bf + ((jb*64 + L)<<3));
    acc = __builtin_amdgcn_mfma_f32_16x16x32_bf16(afrag, b, acc, 0, 0, 0);
#pragma unroll
    for (int q = 0; q < 4; ++q){
      float p1 = b2f(P[(size_t)sQ[q]*512 + jb*16 + cL]);
      float p2 = b2f(P[(size_t)dQ[q]*512 + 256 + jb*16 + cL]);
      float hid = fmaxf(acc[q] + p1 + p2 + bc1v[jb], 0.f);
      osum[q] = fmaf(wc2v[jb], hid, osum[q]);
    }
  }
#pragma unroll
  for (int m = 8; m; m >>= 1)
#pragma unroll
    for (int q = 0; q < 4; ++q) osum[q] += __shfl_xor(osum[q], m, 64);
  if (cL == 0){
#pragma unroll
    for (int q = 0; q < 4; ++q) outp[eQ[q]] = osum[q] + bc2v;
  }
}

extern "C" void kernel_launch(void* const* d_in, const int* in_sizes, int n_in,
                              void* d_out, int out_size, void* d_ws, size_t ws_size,
                              hipStream_t stream)
{
  const float* x   = (const float*)d_in[0];
  const float* h0  = (const float*)d_in[1];
  const int*   ei  = (const int*)d_in[2];
  const float* ea  = (const float*)d_in[3];
  const float* Wih = (const float*)d_in[4];
  const float* Whh = (const float*)d_in[5];
  const float* bih = (const float*)d_in[6];
  const float* bhh = (const float*)d_in[7];
  const float* Wl[3] = {(const float*)d_in[8],  (const float*)d_in[11], (const float*)d_in[14]};
  const float* bl[3] = {(const float*)d_in[9],  (const float*)d_in[12], (const float*)d_in[15]};
  const float* Wr[3] = {(const float*)d_in[10], (const float*)d_in[13], (const float*)d_in[16]};
  const float* Wc1 = (const float*)d_in[17];
  const float* bc1 = (const float*)d_in[18];
  const float* Wc2 = (const float*)d_in[19];
  const float* bc2 = (const float*)d_in[20];

  float* out  = (float*)d_out;
  float* hfin = (float*)d_out + N_EDGES;

  char* wp = (char*)d_ws;
  auto alloc = [&](size_t bytes) -> void* {
    void* p = (void*)wp; wp += (bytes + 255) & ~(size_t)255; return p;
  };
  u16* xb   = (u16*)alloc((size_t)NPAD*128*2);
  u16* h0b  = (u16*)alloc((size_t)NPAD*128*2);
  u16* hA   = (u16*)alloc((size_t)NPAD*128*2);
  u16* hB   = (u16*)alloc((size_t)NPAD*128*2);
  u16* mb   = (u16*)alloc((size_t)NPAD*128*2);
  u16* GP   = (u16*)alloc((size_t)NPAD*512*2);
  u16* Wg_g = (u16*)alloc((size_t)16384*16);
  u16* Wg_s0= (u16*)alloc((size_t)4096*16);
  u16* Wg_s1= (u16*)alloc((size_t)4096*16);
  u16* Wg_s2= (u16*)alloc((size_t)4096*16);
  u16* Wg_p = (u16*)alloc((size_t)8192*16);
  int* counts=(int*)alloc((size_t)N_NODES*4);
  int* cursor=(int*)alloc((size_t)N_NODES*4);
  int* offs  =(int*)alloc((size_t)(N_NODES+1)*4);
  int* lstS  =(int*)alloc((size_t)N_EDGES*4);
  int* lstD  =(int*)alloc((size_t)N_EDGES*4);
  int* lstE  =(int*)alloc((size_t)N_EDGES*4);
  u16* Wg_sl[3] = {Wg_s0, Wg_s1, Wg_s2};

  const dim3 b256(256);

  // casts + CSR + weight packs
  k_cast<<<dim3(6256), b256, 0, stream>>>(x,  xb);
  k_cast<<<dim3(6256), b256, 0, stream>>>(h0, h0b);
  hipMemsetAsync(counts, 0, (size_t)N_NODES*4, stream);
  k_count<<<dim3((N_EDGES+255)/256), b256, 0, stream>>>(ei + N_EDGES, counts);
  k_scan<<<dim3(1), dim3(1024), 0, stream>>>(counts, offs, cursor);
  k_fill<<<dim3((N_EDGES+255)/256), b256, 0, stream>>>(ei, cursor, lstS, lstD, lstE);
  k_pack_gru<<<dim3(64), b256, 0, stream>>>(Wih, Whh, Wg_g);
  for (int l = 0; l < 3; ++l)
    k_pack_sage<<<dim3(16), b256, 0, stream>>>(Wl[l], Wr[l], Wg_sl[l]);
  k_pack_p<<<dim3(32), b256, 0, stream>>>(Wc1, Wg_p);

  // GRU
  k_mm<8,0,512><<<dim3(782,4), b256, 0, stream>>>(xb, h0b, Wg_g, nullptr, nullptr, GP);
  k_gates<<<dim3(6250), b256, 0, stream>>>(GP, h0, bih, bhh, hA);

  // 3x SAGE (bf16 pipeline; layer 3 also writes f32 h to d_out)
  k_agg<<<dim3(12512), b256, 0, stream>>>(hA, offs, lstS, mb);
  k_mm<8,1,128><<<dim3(782,1), b256, 0, stream>>>(mb, hA, Wg_s0, bl[0], nullptr, hB);
  k_agg<<<dim3(12512), b256, 0, stream>>>(hB, offs, lstS, mb);
  k_mm<8,1,128><<<dim3(782,1), b256, 0, stream>>>(mb, hB, Wg_s1, bl[1], nullptr, hA);
  k_agg<<<dim3(12512), b256, 0, stream>>>(hA, offs, lstS, mb);
  k_mm<8,2,128><<<dim3(782,1), b256, 0, stream>>>(mb, hA, Wg_s2, bl[2], hfin, hB);

  // P = h3 @ [A1;A2]^T (bf16), then per-edge classifier in CSR order
  k_mm<4,0,512><<<dim3(782,4), b256, 0, stream>>>(hB, hB, Wg_p, nullptr, nullptr, GP);
  k_edge<<<dim3(9375), b256, 0, stream>>>(lstS, lstD, lstE, ea, GP, Wc1, bc1, Wc2, bc2, out);
}

// Round 5
// 573.861 us; speedup vs baseline: 2.6871x; 1.1536x over previous
//
#include <hip/hip_runtime.h>
#include <hip/hip_bf16.h>

#define N_NODES 100000
#define NPAD    100096
#define N_EDGES 600000
#define SCAN_B  98

typedef unsigned short u16;
typedef unsigned int u32;
typedef short bf16x8 __attribute__((ext_vector_type(8)));
typedef float f32x4 __attribute__((ext_vector_type(4)));

__device__ __forceinline__ float4 ld4(const float* p){ return *(const float4*)p; }
__device__ __forceinline__ float sigm(float v){ return 1.0f/(1.0f + __expf(-v)); }
__device__ __forceinline__ float tanh_fast(float v){
  float e = __expf(-2.0f*fabsf(v));
  float r = (1.0f - e)/(1.0f + e);
  return copysignf(r, v);
}
// f32 -> bf16 bits, RNE
__device__ __forceinline__ u32 bfr(float f){
  u32 u = __float_as_uint(f);
  return (u + 0x7FFFu + ((u>>16)&1u)) >> 16;
}
__device__ __forceinline__ float b2f(u16 b){ return __uint_as_float(((u32)b)<<16); }
__device__ __forceinline__ uint4 pack8(float4 a, float4 b){
  uint4 r;
  r.x = bfr(a.x) | (bfr(a.y)<<16);
  r.y = bfr(a.z) | (bfr(a.w)<<16);
  r.z = bfr(b.x) | (bfr(b.y)<<16);
  r.w = bfr(b.z) | (bfr(b.w)<<16);
  return r;
}
__device__ __forceinline__ void gload16(const void* g, void* l){
  __builtin_amdgcn_global_load_lds((__attribute__((address_space(1))) void*)(g),
                                   (__attribute__((address_space(3))) void*)(l), 16, 0, 0);
}

// ==================== f32 -> bf16 cast with row padding ====================
__global__ __launch_bounds__(256) void k_cast(const float* __restrict__ src, u16* __restrict__ dst){
  int idx = blockIdx.x*256 + threadIdx.x;      // NPAD*16 exact
  int row = idx >> 4, c8 = (idx & 15) << 3;
  float4 v0 = {0,0,0,0}, v1 = {0,0,0,0};
  if (row < N_NODES){
    v0 = ld4(src + (size_t)row*128 + c8);
    v1 = ld4(src + (size_t)row*128 + c8 + 4);
  }
  *(uint4*)(dst + (size_t)row*128 + c8) = pack8(v0, v1);
}

// ==================== weight pack kernels (MFMA B-fragment layout) ====================
// GRU pack with gate interleave: packed col p: j=p>>4, cL=p&15; gate=j&3, c=(j>>2)*16+cL
__global__ void k_pack_gru(const float* __restrict__ Wih, const float* __restrict__ Whh,
                           u16* __restrict__ Wg){
  int cI = blockIdx.x*256 + threadIdx.x;       // 16384
  int lane = cI&63, grp = (cI>>6)&7, ks = (cI>>9)&7, nb = cI>>12;
  int g = grp & 3;
  int c = (nb*2 + (grp>>2))*16 + (lane&15);    // output col in [0,128)
  int kg = ks*32 + ((lane>>4)<<3);
  bool xs = kg < 128;
  const float* src = nullptr;
  if (g == 0)      src = xs ? Wih + (size_t)c*128 + kg       : Whh + (size_t)c*128 + kg-128;
  else if (g == 1) src = xs ? Wih + (size_t)(128+c)*128 + kg : Whh + (size_t)(128+c)*128 + kg-128;
  else if (g == 2) src = xs ? Wih + (size_t)(256+c)*128 + kg : nullptr;
  else             src = xs ? nullptr                        : Whh + (size_t)(256+c)*128 + kg-128;
  float4 v0 = {0,0,0,0}, v1 = {0,0,0,0};
  if (src){ v0 = ld4(src); v1 = ld4(src+4); }
  ((uint4*)Wg)[cI] = pack8(v0, v1);
}

__global__ void k_pack_sage(const float* __restrict__ Wl, const float* __restrict__ Wr,
                            u16* __restrict__ Wg){
  int c = blockIdx.x*256 + threadIdx.x;        // 4096
  int lane = c&63, grp = (c>>6)&7, ks = c>>9;
  int col = grp*16 + (lane&15);
  int kg = ks*32 + ((lane>>4)<<3);
  const float* src = (kg < 128) ? Wl + (size_t)col*128 + kg : Wr + (size_t)col*128 + kg-128;
  ((uint4*)Wg)[c] = pack8(ld4(src), ld4(src+4));
}

__global__ void k_pack_p(const float* __restrict__ Wc1, u16* __restrict__ Wg){
  int c = blockIdx.x*256 + threadIdx.x;        // 8192
  int lane = c&63, grp = (c>>6)&7, ks = (c>>9)&3, nb = c>>11;
  int col = nb*128 + grp*16 + (lane&15);
  int kg = ks*32 + ((lane>>4)<<3);
  const float* src = (col < 256) ? Wc1 + (size_t)col*288 + kg
                                 : Wc1 + (size_t)(col-256)*288 + 128 + kg;
  ((uint4*)Wg)[c] = pack8(ld4(src), ld4(src+4));
}

// ==================== MFMA GEMM: C = [A1|A2] @ Wp^T (A bf16, padded rows) ====================
// EPI 0: bf16 [NPAD,512]; 1: relu+bias bf16 [NPAD,128]; 2: EPI1 + f32 guarded store;
// 3: fused GRU gates (interleaved Wg layout) -> bf16 h [NPAD,128].
template<int NK, int EPI, int NOUT>
__global__ __launch_bounds__(256) void k_mm(
    const u16* __restrict__ A1, const u16* __restrict__ A2,
    const u16* __restrict__ Wp, const float* __restrict__ bias,
    float* __restrict__ outF, u16* __restrict__ outB,
    const float* __restrict__ h0, const float* __restrict__ bih, const float* __restrict__ bhh)
{
  __shared__ __align__(16) char smem[16384];   // A: [0,8K) B: [8K,16K)
  const int t = threadIdx.x, L = t & 63, w = t >> 6;
  const int mw = w >> 1, nw = w & 1;
  const int i0 = blockIdx.x * 128, by = blockIdx.y;
  const f32x4 z4 = {0.f,0.f,0.f,0.f};
  f32x4 acc[4][4];
#pragma unroll
  for (int i=0;i<4;++i)
#pragma unroll
  for (int j=0;j<4;++j) acc[i][j] = z4;

  for (int ks = 0; ks < NK; ++ks){
    if (ks) __syncthreads();
    {
      const u16* src = Wp + ((size_t)(by*NK + ks) << 12);
#pragma unroll
      for (int c = 0; c < 2; ++c){
        int cw = w*2 + c;
        gload16(src + cw*512 + L*8, smem + 8192 + cw*1024);
      }
    }
#pragma unroll
    for (int sh = 0; sh < 2; ++sh){
      int s = t + sh*256;
      int l2 = s & 63;
      int row = i0 + ((s>>6)<<4) + (l2 & 15);
      int kg = ks*32 + ((l2>>4)<<3);
      const u16* src = (ks < 4) ? A1 + (size_t)row*128 + kg
                                : A2 + (size_t)row*128 + kg - 128;
      gload16(src, smem + s*16);
    }
    __syncthreads();
    bf16x8 a[4], b[4];
#pragma unroll
    for (int i = 0; i < 4; ++i) a[i] = *(const bf16x8*)(smem + ((mw*4+i)*64 + L)*16);
#pragma unroll
    for (int j = 0; j < 4; ++j) b[j] = *(const bf16x8*)(smem + 8192 + ((nw*4+j)*64 + L)*16);
#pragma unroll
    for (int i = 0; i < 4; ++i)
#pragma unroll
      for (int j = 0; j < 4; ++j)
        acc[i][j] = __builtin_amdgcn_mfma_f32_16x16x32_bf16(a[i], b[j], acc[i][j], 0, 0, 0);
  }
  const int r4 = (L>>4)*4, cL = L&15;
  if (EPI == 3){
    const int c = (by*2 + nw)*16 + cL;
    const float br = bih[c]     + bhh[c];
    const float bz = bih[128+c] + bhh[128+c];
    const float bi = bih[256+c];
    const float bh = bhh[256+c];
#pragma unroll
    for (int i = 0; i < 4; ++i){
      int rbase = i0 + mw*64 + i*16 + r4;
#pragma unroll
      for (int q = 0; q < 4; ++q){
        int row = rbase + q;
        float rr = sigm(acc[i][0][q] + br);
        float zz = sigm(acc[i][1][q] + bz);
        float nn = tanh_fast(acc[i][2][q] + bi + rr*(acc[i][3][q] + bh));
        float h0v = (row < N_NODES) ? h0[(size_t)row*128 + c] : 0.f;
        outB[(size_t)row*128 + c] = (u16)bfr((1.f - zz)*nn + zz*h0v);
      }
    }
  } else {
#pragma unroll
    for (int i = 0; i < 4; ++i){
      int rbase = i0 + mw*64 + i*16 + r4;
#pragma unroll
      for (int j = 0; j < 4; ++j){
        int col = by*128 + nw*64 + j*16 + cL;
#pragma unroll
        for (int q = 0; q < 4; ++q){
          int row = rbase + q;
          float v = acc[i][j][q];
          if (EPI == 0){
            outB[(size_t)row*NOUT + col] = (u16)bfr(v);
          } else {
            float rv = fmaxf(v + bias[col], 0.f);
            outB[(size_t)row*NOUT + col] = (u16)bfr(rv);
            if (EPI == 2 && row < N_NODES) outF[(size_t)row*NOUT + col] = rv;
          }
        }
      }
    }
  }
}

// ==================== CSR build ====================
__global__ void k_count(const int* __restrict__ dst, int* __restrict__ counts){
  int e = blockIdx.x*256 + threadIdx.x;
  if (e < N_EDGES) atomicAdd(&counts[dst[e]], 1);
}

__global__ __launch_bounds__(1024) void k_scan1(const int* __restrict__ counts,
    int* __restrict__ offs, int* __restrict__ bsum)
{
  __shared__ int wsum[16];
  const int t = threadIdx.x, lane = t & 63, w = t >> 6;
  int i = blockIdx.x*1024 + t;
  int v = (i < N_NODES) ? counts[i] : 0;
  int s = v;
#pragma unroll
  for (int d = 1; d < 64; d <<= 1){ int u = __shfl_up(s, d, 64); if (lane >= d) s += u; }
  if (lane == 63) wsum[w] = s;
  __syncthreads();
  if (w == 0){
    int ws = (lane < 16) ? wsum[lane] : 0;
#pragma unroll
    for (int d = 1; d < 16; d <<= 1){ int u = __shfl_up(ws, d, 64); if (lane >= d) ws += u; }
    if (lane < 16) wsum[lane] = ws;
  }
  __syncthreads();
  int wbase = (w == 0) ? 0 : wsum[w-1];
  if (i < N_NODES) offs[i] = wbase + s - v;
  if (t == 0) bsum[blockIdx.x] = wsum[15];
}

__global__ void k_scan2(int* __restrict__ bsum, int* __restrict__ offs){
  __shared__ int wtot;
  const int t = threadIdx.x, lane = t & 63, w = t >> 6;  // 128 threads
  int v = (t < SCAN_B) ? bsum[t] : 0;
  int s = v;
#pragma unroll
  for (int d = 1; d < 64; d <<= 1){ int u = __shfl_up(s, d, 64); if (lane >= d) s += u; }
  if (t == 63) wtot = s;
  __syncthreads();
  int base = (w == 1) ? wtot : 0;
  int excl = base + s - v;
  if (t < SCAN_B) bsum[t] = excl;
  if (t == SCAN_B-1) offs[N_NODES] = excl + v;
}

__global__ __launch_bounds__(1024) void k_scan3(const int* __restrict__ bsum,
    int* __restrict__ offs, int* __restrict__ cursor)
{
  int i = blockIdx.x*1024 + threadIdx.x;
  if (i < N_NODES){
    int o = offs[i] + bsum[blockIdx.x];
    offs[i] = o; cursor[i] = o;
  }
}

__global__ void k_fill(const int* __restrict__ ei, int* __restrict__ cursor,
                       int* __restrict__ lstS, int* __restrict__ lstD, int* __restrict__ lstE){
  int e = blockIdx.x*256 + threadIdx.x;
  if (e < N_EDGES){
    int s = ei[e], d = ei[N_EDGES + e];
    int slot = atomicAdd(&cursor[d], 1);
    lstS[slot] = s; lstD[slot] = d; lstE[slot] = e;
  }
}

// ==================== mean aggregation (bf16): 32 lanes per node ====================
__global__ __launch_bounds__(256) void k_agg(const u16* __restrict__ hb,
    const int* __restrict__ offs, const int* __restrict__ lst, u16* __restrict__ meanb)
{
  const int node = blockIdx.x*8 + (threadIdx.x >> 5);
  if (node >= NPAD) return;
  const int l32 = threadIdx.x & 31;
  int beg = 0, end = 0;
  if (node < N_NODES){ beg = offs[node]; end = offs[node+1]; }
  float a0=0.f, a1=0.f, a2=0.f, a3=0.f;
  for (int p = beg; p < end; ++p){
    int s = lst[p];
    uint2 v = *(const uint2*)(hb + (size_t)s*128 + l32*4);
    a0 += __uint_as_float(v.x<<16); a1 += __uint_as_float(v.x & 0xFFFF0000u);
    a2 += __uint_as_float(v.y<<16); a3 += __uint_as_float(v.y & 0xFFFF0000u);
  }
  float inv = 1.f / fmaxf((float)(end - beg), 1.f);
  uint2 o;
  o.x = bfr(a0*inv) | (bfr(a1*inv)<<16);
  o.y = bfr(a2*inv) | (bfr(a3*inv)<<16);
  *(uint2*)(meanb + (size_t)node*128 + l32*4) = o;
}

// ==================== per-edge classifier: transposed MFMA + vector gathers ====================
// E^T = A3 @ ea^T: lane owns edge (L&15), features jb*16 + (L>>4)*4 + q (q contiguous!)
__global__ __launch_bounds__(256) void k_edge(
    const int* __restrict__ lstS, const int* __restrict__ lstD, const int* __restrict__ lstE,
    const float* __restrict__ ea, const u16* __restrict__ P,
    const float* __restrict__ Wc1, const float* __restrict__ bc1,
    const float* __restrict__ Wc2, const float* __restrict__ bc2,
    float* __restrict__ outp)
{
  __shared__ __align__(16) u16 Bf[16*64*8];    // 16KB: A3 as MFMA A-frags
  __shared__ float sb[256], sw[256];
  const int t = threadIdx.x, L = t & 63, w = t >> 6;
#pragma unroll
  for (int i = 0; i < 4; ++i){
    int c = t + i*256;
    int lc = c & 63;
    int j = ((c>>6)<<4) + (lc & 15), k0 = (lc >> 4) << 3;
    const float* src = Wc1 + (size_t)j*288 + 256 + k0;
    *(uint4*)(Bf + c*8) = pack8(ld4(src), ld4(src+4));
  }
  sb[t] = bc1[t];
  sw[t] = Wc2[t];
  const int cL = L & 15, part = L >> 4;
  const float bc2v = bc2[0];
  const int pos0 = blockIdx.x*64 + w*16;
  // ea as B-frag: edge = lane&15, k = part*8..+8
  bf16x8 eafrag;
  const int e = lstE[pos0 + cL];
  {
    const float* src = ea + (size_t)e*32 + part*8;
    uint4 pk = pack8(ld4(src), ld4(src+4));
    eafrag = *(bf16x8*)&pk;
  }
  const int s = lstS[pos0 + cL], d = lstD[pos0 + cL];
  const u16* p1base = P + (size_t)s*512 + part*4;
  const u16* p2base = P + (size_t)d*512 + 256 + part*4;
  __syncthreads();
  float osum = 0.f;
#pragma unroll
  for (int jb = 0; jb < 16; ++jb){
    f32x4 acc = {0.f,0.f,0.f,0.f};
    bf16x8 a = *(const bf16x8*)(Bf + ((jb*64 + L)<<3));
    acc = __builtin_amdgcn_mfma_f32_16x16x32_bf16(a, eafrag, acc, 0, 0, 0);
    uint2 u1 = *(const uint2*)(p1base + jb*16);
    uint2 u2 = *(const uint2*)(p2base + jb*16);
    float4 bb = *(const float4*)&sb[jb*16 + part*4];
    float4 ww = *(const float4*)&sw[jb*16 + part*4];
    float p1v[4], p2v[4];
    p1v[0]=__uint_as_float(u1.x<<16); p1v[1]=__uint_as_float(u1.x&0xFFFF0000u);
    p1v[2]=__uint_as_float(u1.y<<16); p1v[3]=__uint_as_float(u1.y&0xFFFF0000u);
    p2v[0]=__uint_as_float(u2.x<<16); p2v[1]=__uint_as_float(u2.x&0xFFFF0000u);
    p2v[2]=__uint_as_float(u2.y<<16); p2v[3]=__uint_as_float(u2.y&0xFFFF0000u);
    float bbv[4]={bb.x,bb.y,bb.z,bb.w}, wwv[4]={ww.x,ww.y,ww.z,ww.w};
#pragma unroll
    for (int q = 0; q < 4; ++q){
      float hid = fmaxf(acc[q] + p1v[q] + p2v[q] + bbv[q], 0.f);
      osum = fmaf(wwv[q], hid, osum);
    }
  }
  osum += __shfl_xor(osum, 16, 64);
  osum += __shfl_xor(osum, 32, 64);
  if (L < 16) outp[e] = osum + bc2v;
}

extern "C" void kernel_launch(void* const* d_in, const int* in_sizes, int n_in,
                              void* d_out, int out_size, void* d_ws, size_t ws_size,
                              hipStream_t stream)
{
  const float* x   = (const float*)d_in[0];
  const float* h0  = (const float*)d_in[1];
  const int*   ei  = (const int*)d_in[2];
  const float* ea  = (const float*)d_in[3];
  const float* Wih = (const float*)d_in[4];
  const float* Whh = (const float*)d_in[5];
  const float* bih = (const float*)d_in[6];
  const float* bhh = (const float*)d_in[7];
  const float* Wl[3] = {(const float*)d_in[8],  (const float*)d_in[11], (const float*)d_in[14]};
  const float* bl[3] = {(const float*)d_in[9],  (const float*)d_in[12], (const float*)d_in[15]};
  const float* Wr[3] = {(const float*)d_in[10], (const float*)d_in[13], (const float*)d_in[16]};
  const float* Wc1 = (const float*)d_in[17];
  const float* bc1 = (const float*)d_in[18];
  const float* Wc2 = (const float*)d_in[19];
  const float* bc2 = (const float*)d_in[20];

  float* out  = (float*)d_out;
  float* hfin = (float*)d_out + N_EDGES;

  char* wp = (char*)d_ws;
  auto alloc = [&](size_t bytes) -> void* {
    void* p = (void*)wp; wp += (bytes + 255) & ~(size_t)255; return p;
  };
  u16* xb   = (u16*)alloc((size_t)NPAD*128*2);
  u16* h0b  = (u16*)alloc((size_t)NPAD*128*2);
  u16* hA   = (u16*)alloc((size_t)NPAD*128*2);
  u16* hB   = (u16*)alloc((size_t)NPAD*128*2);
  u16* mb   = (u16*)alloc((size_t)NPAD*128*2);
  u16* GP   = (u16*)alloc((size_t)NPAD*512*2);
  u16* Wg_g = (u16*)alloc((size_t)16384*16);
  u16* Wg_s0= (u16*)alloc((size_t)4096*16);
  u16* Wg_s1= (u16*)alloc((size_t)4096*16);
  u16* Wg_s2= (u16*)alloc((size_t)4096*16);
  u16* Wg_p = (u16*)alloc((size_t)8192*16);
  int* counts=(int*)alloc((size_t)N_NODES*4);
  int* cursor=(int*)alloc((size_t)N_NODES*4);
  int* offs  =(int*)alloc((size_t)(N_NODES+1)*4);
  int* bsum  =(int*)alloc((size_t)SCAN_B*4);
  int* lstS  =(int*)alloc((size_t)N_EDGES*4);
  int* lstD  =(int*)alloc((size_t)N_EDGES*4);
  int* lstE  =(int*)alloc((size_t)N_EDGES*4);
  u16* Wg_sl[3] = {Wg_s0, Wg_s1, Wg_s2};

  const dim3 b256(256);

  // casts + CSR + weight packs
  k_cast<<<dim3(6256), b256, 0, stream>>>(x,  xb);
  k_cast<<<dim3(6256), b256, 0, stream>>>(h0, h0b);
  (void)hipMemsetAsync(counts, 0, (size_t)N_NODES*4, stream);
  k_count<<<dim3((N_EDGES+255)/256), b256, 0, stream>>>(ei + N_EDGES, counts);
  k_scan1<<<dim3(SCAN_B), dim3(1024), 0, stream>>>(counts, offs, bsum);
  k_scan2<<<dim3(1), dim3(128), 0, stream>>>(bsum, offs);
  k_scan3<<<dim3(SCAN_B), dim3(1024), 0, stream>>>(bsum, offs, cursor);
  k_fill<<<dim3((N_EDGES+255)/256), b256, 0, stream>>>(ei, cursor, lstS, lstD, lstE);
  k_pack_gru<<<dim3(64), b256, 0, stream>>>(Wih, Whh, Wg_g);
  for (int l = 0; l < 3; ++l)
    k_pack_sage<<<dim3(16), b256, 0, stream>>>(Wl[l], Wr[l], Wg_sl[l]);
  k_pack_p<<<dim3(32), b256, 0, stream>>>(Wc1, Wg_p);

  // GRU: fused GEMM + gates -> hA (bf16)
  k_mm<8,3,128><<<dim3(782,4), b256, 0, stream>>>(xb, h0b, Wg_g, nullptr, nullptr, hA, h0, bih, bhh);

  // 3x SAGE (bf16 pipeline; layer 3 also writes f32 h to d_out)
  k_agg<<<dim3(12512), b256, 0, stream>>>(hA, offs, lstS, mb);
  k_mm<8,1,128><<<dim3(782,1), b256, 0, stream>>>(mb, hA, Wg_s0, bl[0], nullptr, hB, nullptr, nullptr, nullptr);
  k_agg<<<dim3(12512), b256, 0, stream>>>(hB, offs, lstS, mb);
  k_mm<8,1,128><<<dim3(782,1), b256, 0, stream>>>(mb, hB, Wg_s1, bl[1], nullptr, hA, nullptr, nullptr, nullptr);
  k_agg<<<dim3(12512), b256, 0, stream>>>(hA, offs, lstS, mb);
  k_mm<8,2,128><<<dim3(782,1), b256, 0, stream>>>(mb, hA, Wg_s2, bl[2], hfin, hB, nullptr, nullptr, nullptr);

  // P = h3 @ [A1;A2]^T (bf16), then per-edge classifier in CSR order
  k_mm<4,0,512><<<dim3(782,4), b256, 0, stream>>>(hB, hB, Wg_p, nullptr, nullptr, GP, nullptr, nullptr, nullptr);
  k_edge<<<dim3(9375), b256, 0, stream>>>(lstS, lstD, lstE, ea, GP, Wc1, bc1, Wc2, bc2, out);
}

// Round 6
// 503.838 us; speedup vs baseline: 3.0606x; 1.1390x over previous
//
#include <hip/hip_runtime.h>
#include <hip/hip_bf16.h>

#define N_NODES 100000
#define NPAD    100096
#define N_EDGES 600000
#define SCAN_B  98

typedef unsigned short u16;
typedef unsigned int u32;
typedef short bf16x8 __attribute__((ext_vector_type(8)));
typedef float f32x4 __attribute__((ext_vector_type(4)));

__device__ __forceinline__ float4 ld4(const float* p){ return *(const float4*)p; }
__device__ __forceinline__ float sigm(float v){ return 1.0f/(1.0f + __expf(-v)); }
__device__ __forceinline__ float tanh_fast(float v){
  float e = __expf(-2.0f*fabsf(v));
  float r = (1.0f - e)/(1.0f + e);
  return copysignf(r, v);
}
// f32 -> bf16 bits, RNE
__device__ __forceinline__ u32 bfr(float f){
  u32 u = __float_as_uint(f);
  return (u + 0x7FFFu + ((u>>16)&1u)) >> 16;
}
__device__ __forceinline__ uint4 pack8(float4 a, float4 b){
  uint4 r;
  r.x = bfr(a.x) | (bfr(a.y)<<16);
  r.y = bfr(a.z) | (bfr(a.w)<<16);
  r.z = bfr(b.x) | (bfr(b.y)<<16);
  r.w = bfr(b.z) | (bfr(b.w)<<16);
  return r;
}
__device__ __forceinline__ void gload16(const void* g, void* l){
  __builtin_amdgcn_global_load_lds((__attribute__((address_space(1))) void*)(g),
                                   (__attribute__((address_space(3))) void*)(l), 16, 0, 0);
}

// ==================== f32 -> bf16 cast with row padding (x and h0 fused) ====================
__global__ __launch_bounds__(256) void k_cast2(const float* __restrict__ s0, const float* __restrict__ s1,
                                               u16* __restrict__ d0, u16* __restrict__ d1){
  int idx = blockIdx.x*256 + threadIdx.x;      // 2*NPAD*16
  const int half = NPAD*16;
  const float* src = (idx < half) ? s0 : s1;
  u16* dst = (idx < half) ? d0 : d1;
  if (idx >= half) idx -= half;
  int row = idx >> 4, c8 = (idx & 15) << 3;
  float4 v0 = {0,0,0,0}, v1 = {0,0,0,0};
  if (row < N_NODES){
    v0 = ld4(src + (size_t)row*128 + c8);
    v1 = ld4(src + (size_t)row*128 + c8 + 4);
  }
  *(uint4*)(dst + (size_t)row*128 + c8) = pack8(v0, v1);
}

// ==================== weight pack kernels (MFMA B-fragment layout) ====================
// GRU pack with gate interleave: packed col p: j=p>>4, cL=p&15; gate=j&3, c=(j>>2)*16+cL
__global__ void k_pack_gru(const float* __restrict__ Wih, const float* __restrict__ Whh,
                           u16* __restrict__ Wg){
  int cI = blockIdx.x*256 + threadIdx.x;       // 16384
  int lane = cI&63, grp = (cI>>6)&7, ks = (cI>>9)&7, nb = cI>>12;
  int g = grp & 3;
  int c = (nb*2 + (grp>>2))*16 + (lane&15);    // output col in [0,128)
  int kg = ks*32 + ((lane>>4)<<3);
  bool xs = kg < 128;
  const float* src = nullptr;
  if (g == 0)      src = xs ? Wih + (size_t)c*128 + kg       : Whh + (size_t)c*128 + kg-128;
  else if (g == 1) src = xs ? Wih + (size_t)(128+c)*128 + kg : Whh + (size_t)(128+c)*128 + kg-128;
  else if (g == 2) src = xs ? Wih + (size_t)(256+c)*128 + kg : nullptr;
  else             src = xs ? nullptr                        : Whh + (size_t)(256+c)*128 + kg-128;
  float4 v0 = {0,0,0,0}, v1 = {0,0,0,0};
  if (src){ v0 = ld4(src); v1 = ld4(src+4); }
  ((uint4*)Wg)[cI] = pack8(v0, v1);
}

__global__ void k_pack_sage(const float* __restrict__ Wl, const float* __restrict__ Wr,
                            u16* __restrict__ Wg){
  int c = blockIdx.x*256 + threadIdx.x;        // 4096
  int lane = c&63, grp = (c>>6)&7, ks = c>>9;
  int col = grp*16 + (lane&15);
  int kg = ks*32 + ((lane>>4)<<3);
  const float* src = (kg < 128) ? Wl + (size_t)col*128 + kg : Wr + (size_t)col*128 + kg-128;
  ((uint4*)Wg)[c] = pack8(ld4(src), ld4(src+4));
}

__global__ void k_pack_p(const float* __restrict__ Wc1, u16* __restrict__ Wg){
  int c = blockIdx.x*256 + threadIdx.x;        // 8192
  int lane = c&63, grp = (c>>6)&7, ks = (c>>9)&3, nb = c>>11;
  int col = nb*128 + grp*16 + (lane&15);
  int kg = ks*32 + ((lane>>4)<<3);
  const float* src = (col < 256) ? Wc1 + (size_t)col*288 + kg
                                 : Wc1 + (size_t)(col-256)*288 + 128 + kg;
  ((uint4*)Wg)[c] = pack8(ld4(src), ld4(src+4));
}

// A3 (edge-attr part of Wc1) as MFMA A-frags for k_edge, prepacked
__global__ void k_pack_e(const float* __restrict__ Wc1, u16* __restrict__ Wg_e){
  int c = blockIdx.x*256 + threadIdx.x;        // 1024
  int lc = c & 63;
  int j = ((c>>6)<<4) + (lc & 15), k0 = (lc >> 4) << 3;
  const float* src = Wc1 + (size_t)j*288 + 256 + k0;
  ((uint4*)Wg_e)[c] = pack8(ld4(src), ld4(src+4));
}

// ==================== MFMA GEMM: C = [A1|A2] @ Wp^T (A bf16, padded rows) ====================
// EPI 0: bf16 [NPAD,512]; 1: relu+bias bf16 [NPAD,128]; 2: EPI1 + f32 guarded store;
// 3: fused GRU gates (interleaved Wg layout) -> bf16 h [NPAD,128].
template<int NK, int EPI, int NOUT>
__global__ __launch_bounds__(256) void k_mm(
    const u16* __restrict__ A1, const u16* __restrict__ A2,
    const u16* __restrict__ Wp, const float* __restrict__ bias,
    float* __restrict__ outF, u16* __restrict__ outB,
    const float* __restrict__ h0, const float* __restrict__ bih, const float* __restrict__ bhh)
{
  __shared__ __align__(16) char smem[16384];   // A: [0,8K) B: [8K,16K)
  const int t = threadIdx.x, L = t & 63, w = t >> 6;
  const int mw = w >> 1, nw = w & 1;
  const int i0 = blockIdx.x * 128, by = blockIdx.y;
  const f32x4 z4 = {0.f,0.f,0.f,0.f};
  f32x4 acc[4][4];
#pragma unroll
  for (int i=0;i<4;++i)
#pragma unroll
  for (int j=0;j<4;++j) acc[i][j] = z4;

  for (int ks = 0; ks < NK; ++ks){
    if (ks) __syncthreads();
    {
      const u16* src = Wp + ((size_t)(by*NK + ks) << 12);
#pragma unroll
      for (int c = 0; c < 2; ++c){
        int cw = w*2 + c;
        gload16(src + cw*512 + L*8, smem + 8192 + cw*1024);
      }
    }
#pragma unroll
    for (int sh = 0; sh < 2; ++sh){
      int s = t + sh*256;
      int l2 = s & 63;
      int row = i0 + ((s>>6)<<4) + (l2 & 15);
      int kg = ks*32 + ((l2>>4)<<3);
      const u16* src = (ks < 4) ? A1 + (size_t)row*128 + kg
                                : A2 + (size_t)row*128 + kg - 128;
      gload16(src, smem + s*16);
    }
    __syncthreads();
    bf16x8 a[4], b[4];
#pragma unroll
    for (int i = 0; i < 4; ++i) a[i] = *(const bf16x8*)(smem + ((mw*4+i)*64 + L)*16);
#pragma unroll
    for (int j = 0; j < 4; ++j) b[j] = *(const bf16x8*)(smem + 8192 + ((nw*4+j)*64 + L)*16);
#pragma unroll
    for (int i = 0; i < 4; ++i)
#pragma unroll
      for (int j = 0; j < 4; ++j)
        acc[i][j] = __builtin_amdgcn_mfma_f32_16x16x32_bf16(a[i], b[j], acc[i][j], 0, 0, 0);
  }
  const int r4 = (L>>4)*4, cL = L&15;
  if (EPI == 3){
    const int c = (by*2 + nw)*16 + cL;
    const float br = bih[c]     + bhh[c];
    const float bz = bih[128+c] + bhh[128+c];
    const float bi = bih[256+c];
    const float bh = bhh[256+c];
#pragma unroll
    for (int i = 0; i < 4; ++i){
      int rbase = i0 + mw*64 + i*16 + r4;
#pragma unroll
      for (int q = 0; q < 4; ++q){
        int row = rbase + q;
        float rr = sigm(acc[i][0][q] + br);
        float zz = sigm(acc[i][1][q] + bz);
        float nn = tanh_fast(acc[i][2][q] + bi + rr*(acc[i][3][q] + bh));
        float h0v = (row < N_NODES) ? h0[(size_t)row*128 + c] : 0.f;
        outB[(size_t)row*128 + c] = (u16)bfr((1.f - zz)*nn + zz*h0v);
      }
    }
  } else {
#pragma unroll
    for (int i = 0; i < 4; ++i){
      int rbase = i0 + mw*64 + i*16 + r4;
#pragma unroll
      for (int j = 0; j < 4; ++j){
        int col = by*128 + nw*64 + j*16 + cL;
#pragma unroll
        for (int q = 0; q < 4; ++q){
          int row = rbase + q;
          float v = acc[i][j][q];
          if (EPI == 0){
            outB[(size_t)row*NOUT + col] = (u16)bfr(v);
          } else {
            float rv = fmaxf(v + bias[col], 0.f);
            outB[(size_t)row*NOUT + col] = (u16)bfr(rv);
            if (EPI == 2 && row < N_NODES) outF[(size_t)row*NOUT + col] = rv;
          }
        }
      }
    }
  }
}

// ==================== CSR build ====================
__global__ void k_count(const int* __restrict__ dst, int* __restrict__ counts){
  int e = blockIdx.x*256 + threadIdx.x;
  if (e < N_EDGES) atomicAdd(&counts[dst[e]], 1);
}

__global__ __launch_bounds__(1024) void k_scan1(const int* __restrict__ counts,
    int* __restrict__ offs, int* __restrict__ bsum)
{
  __shared__ int wsum[16];
  const int t = threadIdx.x, lane = t & 63, w = t >> 6;
  int i = blockIdx.x*1024 + t;
  int v = (i < N_NODES) ? counts[i] : 0;
  int s = v;
#pragma unroll
  for (int d = 1; d < 64; d <<= 1){ int u = __shfl_up(s, d, 64); if (lane >= d) s += u; }
  if (lane == 63) wsum[w] = s;
  __syncthreads();
  if (w == 0){
    int ws = (lane < 16) ? wsum[lane] : 0;
#pragma unroll
    for (int d = 1; d < 16; d <<= 1){ int u = __shfl_up(ws, d, 64); if (lane >= d) ws += u; }
    if (lane < 16) wsum[lane] = ws;
  }
  __syncthreads();
  int wbase = (w == 0) ? 0 : wsum[w-1];
  if (i < N_NODES) offs[i] = wbase + s - v;
  if (t == 0) bsum[blockIdx.x] = wsum[15];
}

__global__ void k_scan2(int* __restrict__ bsum, int* __restrict__ offs){
  __shared__ int wtot;
  const int t = threadIdx.x, lane = t & 63, w = t >> 6;  // 128 threads
  int v = (t < SCAN_B) ? bsum[t] : 0;
  int s = v;
#pragma unroll
  for (int d = 1; d < 64; d <<= 1){ int u = __shfl_up(s, d, 64); if (lane >= d) s += u; }
  if (t == 63) wtot = s;
  __syncthreads();
  int base = (w == 1) ? wtot : 0;
  int excl = base + s - v;
  if (t < SCAN_B) bsum[t] = excl;
  if (t == SCAN_B-1) offs[N_NODES] = excl + v;
}

__global__ __launch_bounds__(1024) void k_scan3(const int* __restrict__ bsum,
    int* __restrict__ offs, int* __restrict__ cursor)
{
  int i = blockIdx.x*1024 + threadIdx.x;
  if (i < N_NODES){
    int o = offs[i] + bsum[blockIdx.x];
    offs[i] = o; cursor[i] = o;
  }
}

__global__ void k_fill(const int* __restrict__ ei, int* __restrict__ cursor,
                       int* __restrict__ lstS, int* __restrict__ lstD, int* __restrict__ lstE){
  int e = blockIdx.x*256 + threadIdx.x;
  if (e < N_EDGES){
    int s = ei[e], d = ei[N_EDGES + e];
    int slot = atomicAdd(&cursor[d], 1);
    lstS[slot] = s; lstD[slot] = d; lstE[slot] = e;
  }
}

// ==================== mean aggregation (bf16): 16 lanes per node, uint4, 2-deep ====================
__global__ __launch_bounds__(256) void k_agg(const u16* __restrict__ hb,
    const int* __restrict__ offs, const int* __restrict__ lst, u16* __restrict__ meanb)
{
  const int node = blockIdx.x*16 + (threadIdx.x >> 4);
  if (node >= NPAD) return;
  const int l16 = threadIdx.x & 15;
  int beg = 0, end = 0;
  if (node < N_NODES){ beg = offs[node]; end = offs[node+1]; }
  float a0=0.f,a1=0.f,a2=0.f,a3=0.f,a4=0.f,a5=0.f,a6=0.f,a7=0.f;
  int p = beg;
  for (; p + 2 <= end; p += 2){
    int s0 = lst[p], s1 = lst[p+1];
    uint4 v0 = *(const uint4*)(hb + (size_t)s0*128 + l16*8);
    uint4 v1 = *(const uint4*)(hb + (size_t)s1*128 + l16*8);
    a0 += __uint_as_float(v0.x<<16); a1 += __uint_as_float(v0.x & 0xFFFF0000u);
    a2 += __uint_as_float(v0.y<<16); a3 += __uint_as_float(v0.y & 0xFFFF0000u);
    a4 += __uint_as_float(v0.z<<16); a5 += __uint_as_float(v0.z & 0xFFFF0000u);
    a6 += __uint_as_float(v0.w<<16); a7 += __uint_as_float(v0.w & 0xFFFF0000u);
    a0 += __uint_as_float(v1.x<<16); a1 += __uint_as_float(v1.x & 0xFFFF0000u);
    a2 += __uint_as_float(v1.y<<16); a3 += __uint_as_float(v1.y & 0xFFFF0000u);
    a4 += __uint_as_float(v1.z<<16); a5 += __uint_as_float(v1.z & 0xFFFF0000u);
    a6 += __uint_as_float(v1.w<<16); a7 += __uint_as_float(v1.w & 0xFFFF0000u);
  }
  if (p < end){
    uint4 v0 = *(const uint4*)(hb + (size_t)lst[p]*128 + l16*8);
    a0 += __uint_as_float(v0.x<<16); a1 += __uint_as_float(v0.x & 0xFFFF0000u);
    a2 += __uint_as_float(v0.y<<16); a3 += __uint_as_float(v0.y & 0xFFFF0000u);
    a4 += __uint_as_float(v0.z<<16); a5 += __uint_as_float(v0.z & 0xFFFF0000u);
    a6 += __uint_as_float(v0.w<<16); a7 += __uint_as_float(v0.w & 0xFFFF0000u);
  }
  float inv = 1.f / fmaxf((float)(end - beg), 1.f);
  uint4 o;
  o.x = bfr(a0*inv) | (bfr(a1*inv)<<16);
  o.y = bfr(a2*inv) | (bfr(a3*inv)<<16);
  o.z = bfr(a4*inv) | (bfr(a5*inv)<<16);
  o.w = bfr(a6*inv) | (bfr(a7*inv)<<16);
  *(uint4*)(meanb + (size_t)node*128 + l16*8) = o;
}

// ==================== per-edge classifier: transposed MFMA + reg-prefetched gathers ====================
// E^T = A3 @ ea^T: lane owns edge (L&15), features jb*16 + (L>>4)*4 + q
__global__ __launch_bounds__(256) void k_edge(
    const int* __restrict__ lstS, const int* __restrict__ lstD, const int* __restrict__ lstE,
    const float* __restrict__ ea, const u16* __restrict__ P, const u16* __restrict__ Wg_e,
    const float* __restrict__ bc1, const float* __restrict__ Wc2, const float* __restrict__ bc2,
    float* __restrict__ outp)
{
  __shared__ __align__(16) u16 Bf[16*64*8];    // 16KB: A3 as MFMA A-frags (prepacked)
  __shared__ float sb[256], sw[256];
  const int t = threadIdx.x, L = t & 63, w = t >> 6;
#pragma unroll
  for (int i = 0; i < 4; ++i){
    int c = t + i*256;
    gload16(Wg_e + c*8, Bf + c*8);
  }
  sb[t] = bc1[t];
  sw[t] = Wc2[t];
  const int cL = L & 15, part = L >> 4;
  const float bc2v = bc2[0];
  const int pos0 = blockIdx.x*64 + w*16;
  const int e = lstE[pos0 + cL];
  const int s = lstS[pos0 + cL], d = lstD[pos0 + cL];
  // ea as B-frag: edge = lane&15, k = part*8..+8
  bf16x8 eafrag;
  {
    const float* src = ea + (size_t)e*32 + part*8;
    uint4 pk = pack8(ld4(src), ld4(src+4));
    eafrag = *(bf16x8*)&pk;
  }
  const u16* p1base = P + (size_t)s*512 + part*4;
  const u16* p2base = P + (size_t)d*512 + 256 + part*4;
  // prefetch ALL 32 gathers into registers (static indices -> VGPRs, ~32 loads in flight)
  uint2 g1[16], g2[16];
#pragma unroll
  for (int jb = 0; jb < 16; ++jb){
    g1[jb] = *(const uint2*)(p1base + jb*16);
    g2[jb] = *(const uint2*)(p2base + jb*16);
  }
  __syncthreads();   // drains vmcnt: Bf staged AND all gathers landed
  float osum = 0.f;
#pragma unroll
  for (int jb = 0; jb < 16; ++jb){
    f32x4 acc = {0.f,0.f,0.f,0.f};
    bf16x8 a = *(const bf16x8*)(Bf + ((jb*64 + L)<<3));
    acc = __builtin_amdgcn_mfma_f32_16x16x32_bf16(a, eafrag, acc, 0, 0, 0);
    float4 bb = *(const float4*)&sb[jb*16 + part*4];
    float4 ww = *(const float4*)&sw[jb*16 + part*4];
    float p1v[4], p2v[4];
    p1v[0]=__uint_as_float(g1[jb].x<<16); p1v[1]=__uint_as_float(g1[jb].x&0xFFFF0000u);
    p1v[2]=__uint_as_float(g1[jb].y<<16); p1v[3]=__uint_as_float(g1[jb].y&0xFFFF0000u);
    p2v[0]=__uint_as_float(g2[jb].x<<16); p2v[1]=__uint_as_float(g2[jb].x&0xFFFF0000u);
    p2v[2]=__uint_as_float(g2[jb].y<<16); p2v[3]=__uint_as_float(g2[jb].y&0xFFFF0000u);
    float bbv[4]={bb.x,bb.y,bb.z,bb.w}, wwv[4]={ww.x,ww.y,ww.z,ww.w};
#pragma unroll
    for (int q = 0; q < 4; ++q){
      float hid = fmaxf(acc[q] + p1v[q] + p2v[q] + bbv[q], 0.f);
      osum = fmaf(wwv[q], hid, osum);
    }
  }
  osum += __shfl_xor(osum, 16, 64);
  osum += __shfl_xor(osum, 32, 64);
  if (L < 16) outp[e] = osum + bc2v;
}

extern "C" void kernel_launch(void* const* d_in, const int* in_sizes, int n_in,
                              void* d_out, int out_size, void* d_ws, size_t ws_size,
                              hipStream_t stream)
{
  const float* x   = (const float*)d_in[0];
  const float* h0  = (const float*)d_in[1];
  const int*   ei  = (const int*)d_in[2];
  const float* ea  = (const float*)d_in[3];
  const float* Wih = (const float*)d_in[4];
  const float* Whh = (const float*)d_in[5];
  const float* bih = (const float*)d_in[6];
  const float* bhh = (const float*)d_in[7];
  const float* Wl[3] = {(const float*)d_in[8],  (const float*)d_in[11], (const float*)d_in[14]};
  const float* bl[3] = {(const float*)d_in[9],  (const float*)d_in[12], (const float*)d_in[15]};
  const float* Wr[3] = {(const float*)d_in[10], (const float*)d_in[13], (const float*)d_in[16]};
  const float* Wc1 = (const float*)d_in[17];
  const float* bc1 = (const float*)d_in[18];
  const float* Wc2 = (const float*)d_in[19];
  const float* bc2 = (const float*)d_in[20];

  float* out  = (float*)d_out;
  float* hfin = (float*)d_out + N_EDGES;

  char* wp = (char*)d_ws;
  auto alloc = [&](size_t bytes) -> void* {
    void* p = (void*)wp; wp += (bytes + 255) & ~(size_t)255; return p;
  };
  u16* xb   = (u16*)alloc((size_t)NPAD*128*2);
  u16* h0b  = (u16*)alloc((size_t)NPAD*128*2);
  u16* hA   = (u16*)alloc((size_t)NPAD*128*2);
  u16* hB   = (u16*)alloc((size_t)NPAD*128*2);
  u16* mb   = (u16*)alloc((size_t)NPAD*128*2);
  u16* GP   = (u16*)alloc((size_t)NPAD*512*2);
  u16* Wg_g = (u16*)alloc((size_t)16384*16);
  u16* Wg_s0= (u16*)alloc((size_t)4096*16);
  u16* Wg_s1= (u16*)alloc((size_t)4096*16);
  u16* Wg_s2= (u16*)alloc((size_t)4096*16);
  u16* Wg_p = (u16*)alloc((size_t)8192*16);
  u16* Wg_e = (u16*)alloc((size_t)1024*16);
  int* counts=(int*)alloc((size_t)N_NODES*4);
  int* cursor=(int*)alloc((size_t)N_NODES*4);
  int* offs  =(int*)alloc((size_t)(N_NODES+1)*4);
  int* bsum  =(int*)alloc((size_t)SCAN_B*4);
  int* lstS  =(int*)alloc((size_t)N_EDGES*4);
  int* lstD  =(int*)alloc((size_t)N_EDGES*4);
  int* lstE  =(int*)alloc((size_t)N_EDGES*4);
  u16* Wg_sl[3] = {Wg_s0, Wg_s1, Wg_s2};

  const dim3 b256(256);

  // casts + CSR + weight packs
  k_cast2<<<dim3(12512), b256, 0, stream>>>(x, h0, xb, h0b);
  (void)hipMemsetAsync(counts, 0, (size_t)N_NODES*4, stream);
  k_count<<<dim3((N_EDGES+255)/256), b256, 0, stream>>>(ei + N_EDGES, counts);
  k_scan1<<<dim3(SCAN_B), dim3(1024), 0, stream>>>(counts, offs, bsum);
  k_scan2<<<dim3(1), dim3(128), 0, stream>>>(bsum, offs);
  k_scan3<<<dim3(SCAN_B), dim3(1024), 0, stream>>>(bsum, offs, cursor);
  k_fill<<<dim3((N_EDGES+255)/256), b256, 0, stream>>>(ei, cursor, lstS, lstD, lstE);
  k_pack_gru<<<dim3(64), b256, 0, stream>>>(Wih, Whh, Wg_g);
  for (int l = 0; l < 3; ++l)
    k_pack_sage<<<dim3(16), b256, 0, stream>>>(Wl[l], Wr[l], Wg_sl[l]);
  k_pack_p<<<dim3(32), b256, 0, stream>>>(Wc1, Wg_p);
  k_pack_e<<<dim3(4), b256, 0, stream>>>(Wc1, Wg_e);

  // GRU: fused GEMM + gates -> hA (bf16)
  k_mm<8,3,128><<<dim3(782,4), b256, 0, stream>>>(xb, h0b, Wg_g, nullptr, nullptr, hA, h0, bih, bhh);

  // 3x SAGE (bf16 pipeline; layer 3 also writes f32 h to d_out)
  k_agg<<<dim3(6256), b256, 0, stream>>>(hA, offs, lstS, mb);
  k_mm<8,1,128><<<dim3(782,1), b256, 0, stream>>>(mb, hA, Wg_s0, bl[0], nullptr, hB, nullptr, nullptr, nullptr);
  k_agg<<<dim3(6256), b256, 0, stream>>>(hB, offs, lstS, mb);
  k_mm<8,1,128><<<dim3(782,1), b256, 0, stream>>>(mb, hB, Wg_s1, bl[1], nullptr, hA, nullptr, nullptr, nullptr);
  k_agg<<<dim3(6256), b256, 0, stream>>>(hA, offs, lstS, mb);
  k_mm<8,2,128><<<dim3(782,1), b256, 0, stream>>>(mb, hA, Wg_s2, bl[2], hfin, hB, nullptr, nullptr, nullptr);

  // P = h3 @ [A1;A2]^T (bf16), then per-edge classifier in CSR order
  k_mm<4,0,512><<<dim3(782,4), b256, 0, stream>>>(hB, hB, Wg_p, nullptr, nullptr, GP, nullptr, nullptr, nullptr);
  k_edge<<<dim3(9375), b256, 0, stream>>>(lstS, lstD, lstE, ea, GP, Wg_e, bc1, Wc2, bc2, out);
}